// Round 3
// baseline (1223.524 us; speedup 1.0000x reference)
//
#include <hip/hip_runtime.h>
#include <hip/hip_bf16.h>
#include <math.h>

// ---------------------------------------------------------------------------
// DFNPureModel round 6:
//   Pre-selection GEMMs (gemm3k): BARRIER-FREE direct-global version.
//   No LDS, no __syncthreads. Each wave loads its MFMA fragments straight
//   from global (B panels are L2-resident: 1-2.25 MB; A streamed) into a
//   manual 2-set register double buffer (named sets s0/s1, static indexing).
//   Compiler emits counted vmcnt waits -> per-wave software pipeline with
//   zero inter-wave coupling. 8 independent waves/CU (VGPR-capped 256).
//   Block swizzle changed to m-chunked XCD mapping: XCD = L&7 owns a
//   contiguous m-range, n-fastest within -> A-tile + B panel are L2 hits.
//   MFMA burst order (hh, hl, lh) identical to round 5 -> bitwise-same acc.
//   gemm_post / attn / transposes reverted verbatim to the round-4 config
//   (best measured "other" time); round-5 EFB-bf16 ef epilogue + slim
//   gather kept.
// ---------------------------------------------------------------------------

typedef __attribute__((ext_vector_type(8))) short bf16x8;
typedef __attribute__((ext_vector_type(4))) float f32x4;

__device__ __forceinline__ float gelu_exact(float x) {
    return 0.5f * x * (1.0f + erff(x * 0.7071067811865476f));
}

__device__ __forceinline__ void async_copy16(const void* g, void* l) {
    __builtin_amdgcn_global_load_lds(
        (const __attribute__((address_space(1))) unsigned int*)g,
        (__attribute__((address_space(3))) unsigned int*)l, 16, 0, 0);
}

// ===================== elementwise fp32 -> (hi, lo) bf16 split ==============
__global__ __launch_bounds__(256) void split_kernel(
    const float* __restrict__ in,
    __hip_bfloat16* __restrict__ hi, __hip_bfloat16* __restrict__ lo)
{
    const int i4 = blockIdx.x * 256 + threadIdx.x;
    const float4 v = ((const float4*)in)[i4];
    __hip_bfloat16 h0 = __float2bfloat16(v.x);
    __hip_bfloat16 h1 = __float2bfloat16(v.y);
    __hip_bfloat16 h2 = __float2bfloat16(v.z);
    __hip_bfloat16 h3 = __float2bfloat16(v.w);
    __hip_bfloat16 l0 = __float2bfloat16(v.x - __bfloat162float(h0));
    __hip_bfloat16 l1 = __float2bfloat16(v.y - __bfloat162float(h1));
    __hip_bfloat16 l2 = __float2bfloat16(v.z - __bfloat162float(h2));
    __hip_bfloat16 l3 = __float2bfloat16(v.w - __bfloat162float(h3));
    union { __hip_bfloat16 h[4]; short4 s; } uh, ul;
    uh.h[0] = h0; uh.h[1] = h1; uh.h[2] = h2; uh.h[3] = h3;
    ul.h[0] = l0; ul.h[1] = l1; ul.h[2] = l2; ul.h[3] = l3;
    ((short4*)hi)[i4] = uh.s;
    ((short4*)lo)[i4] = ul.s;
}

// ============ W [K][N] fp32 -> WT hi/lo [Npad][K] bf16 (zero-padded) ========
__global__ __launch_bounds__(256) void transpose_split_kernel(
    const float* __restrict__ in,
    __hip_bfloat16* __restrict__ outH, __hip_bfloat16* __restrict__ outL,
    int K, int N)
{
    __shared__ float tile[32][33];
    const int k0 = blockIdx.y * 32, n0 = blockIdx.x * 32;
    const int t = threadIdx.x;
    const int lr = t >> 5, lc = t & 31;
    #pragma unroll
    for (int p = 0; p < 4; p++) {
        const int r = p * 8 + lr;
        const int n = n0 + lc;
        tile[r][lc] = (n < N) ? in[(size_t)(k0 + r) * N + n] : 0.f;
    }
    __syncthreads();
    #pragma unroll
    for (int p = 0; p < 4; p++) {
        const int r = p * 8 + lr;
        const float v = tile[lc][r];
        const __hip_bfloat16 h = __float2bfloat16(v);
        const __hip_bfloat16 l = __float2bfloat16(v - __bfloat162float(h));
        outH[(size_t)(n0 + r) * K + k0 + lc] = h;
        outL[(size_t)(n0 + r) * K + k0 + lc] = l;
    }
}

// ================= init: IMP = 0, CRD = bc (atomic accumulators) ============
__global__ __launch_bounds__(256) void init_kernel(
    float* __restrict__ IMP, float* __restrict__ CRD,
    const float* __restrict__ bc)
{
    const int t = blockIdx.x * 256 + threadIdx.x;   // 0..32767
    IMP[t] = 0.f;
    ((float2*)CRD)[t] = make_float2(bc[0], bc[1]);
}

// ===================== bf16x3 split-MFMA GEMM (pre-selection) ===============
// Direct-global, barrier-free. C = act(A @ BT^T + bias [+ rank2]).
// A = Ahi+Alo [M][512], BT = Bhi+Blo [Npad][512].
// 128x128 block tile, 4 waves 2x2 (wave tile 64x64), 16x16x32 MFMA,
// 3 MFMA per fragment pair, 2-set register double buffer, no LDS.
// EFMODE: states bf16 (cols 2..1025), coords fp32 (cols 0..1),
//         squared-importance atomicAdd (cols < 1027).
// FUSEC:  coords = C @ Wc accumulated via atomicAdd into CRD.
template<bool GELU, bool RANK2, bool EFMODE, bool FUSEC>
__global__ __launch_bounds__(256, 2) void gemm3k(
    const __hip_bfloat16* __restrict__ Ahi, const __hip_bfloat16* __restrict__ Alo,
    const __hip_bfloat16* __restrict__ Bhi, const __hip_bfloat16* __restrict__ Blo,
    const float* __restrict__ bias,
    __hip_bfloat16* __restrict__ Chi, __hip_bfloat16* __restrict__ Clo,
    __hip_bfloat16* __restrict__ EFB, float* __restrict__ EFC,
    float* __restrict__ IMP,
    const float* __restrict__ A2, const float* __restrict__ W2r,
    float* __restrict__ CRD, const float* __restrict__ Wc)
{
    const int t = threadIdx.x;
    const int wave = t >> 6, lane = t & 63;
    const int wave_m = wave >> 1, wave_n = wave & 1;
    const int fr = lane & 15, quad = lane >> 4;
    // m-chunked XCD mapping: XCD x = L&7 owns m-blocks [x*(gy/8), ...),
    // n-fastest within -> A-tile reused by gx consecutive blocks on one XCD,
    // B panel L2-resident per XCD.
    const int gx = gridDim.x;                 // n-blocks (4 or 9)
    const int L = blockIdx.y * gx + blockIdx.x;
    const int xcd = L & 7, kk_ = L >> 3;
    const int m_blk = xcd * (gridDim.y >> 3) + kk_ / gx;
    const int n_blk = kk_ % gx;
    const int m0 = m_blk * 128;
    const int n0 = n_blk * 128;

    // fragment base pointers (frag i at + i*16*512 elements; k-step adds kk)
    const __hip_bfloat16* pAh = Ahi + (size_t)(m0 + wave_m * 64 + fr) * 512 + quad * 8;
    const __hip_bfloat16* pAl = Alo + (size_t)(m0 + wave_m * 64 + fr) * 512 + quad * 8;
    const __hip_bfloat16* pBh = Bhi + (size_t)(n0 + wave_n * 64 + fr) * 512 + quad * 8;
    const __hip_bfloat16* pBl = Blo + (size_t)(n0 + wave_n * 64 + fr) * 512 + quad * 8;

    f32x4 acc[4][4] = {};

    struct FragSet { bf16x8 ah[4], al[4], bh[4], bl[4]; };
    FragSet s0, s1;

#define LOAD_SET(S, KK) do {                                              \
        _Pragma("unroll")                                                 \
        for (int i_ = 0; i_ < 4; i_++) {                                  \
            S.ah[i_] = *(const bf16x8*)(pAh + (size_t)i_ * 8192 + (KK));  \
            S.al[i_] = *(const bf16x8*)(pAl + (size_t)i_ * 8192 + (KK));  \
            S.bh[i_] = *(const bf16x8*)(pBh + (size_t)i_ * 8192 + (KK));  \
            S.bl[i_] = *(const bf16x8*)(pBl + (size_t)i_ * 8192 + (KK));  \
        }                                                                 \
    } while (0)

#define MFMA_SET(S) do {                                                  \
        _Pragma("unroll")                                                 \
        for (int i_ = 0; i_ < 4; i_++)                                    \
            _Pragma("unroll")                                             \
            for (int j_ = 0; j_ < 4; j_++)                                \
                acc[i_][j_] = __builtin_amdgcn_mfma_f32_16x16x32_bf16(    \
                    S.ah[i_], S.bh[j_], acc[i_][j_], 0, 0, 0);            \
        _Pragma("unroll")                                                 \
        for (int i_ = 0; i_ < 4; i_++)                                    \
            _Pragma("unroll")                                             \
            for (int j_ = 0; j_ < 4; j_++)                                \
                acc[i_][j_] = __builtin_amdgcn_mfma_f32_16x16x32_bf16(    \
                    S.ah[i_], S.bl[j_], acc[i_][j_], 0, 0, 0);            \
        _Pragma("unroll")                                                 \
        for (int i_ = 0; i_ < 4; i_++)                                    \
            _Pragma("unroll")                                             \
            for (int j_ = 0; j_ < 4; j_++)                                \
                acc[i_][j_] = __builtin_amdgcn_mfma_f32_16x16x32_bf16(    \
                    S.al[i_], S.bh[j_], acc[i_][j_], 0, 0, 0);            \
    } while (0)

    LOAD_SET(s0, 0);
    for (int step = 0; step < 16; step += 2) {
        LOAD_SET(s1, (step + 1) << 5);
        MFMA_SET(s0);
        const int kn = ((step + 2 < 16) ? (step + 2) : 15) << 5;  // guarded
        LOAD_SET(s0, kn);
        MFMA_SET(s1);
    }
#undef LOAD_SET
#undef MFMA_SET

    // epilogue: row = m0 + wave_m*64 + i*16 + quad*4 + r,
    //           col = n0 + wave_n*64 + j*16 + fr
    #pragma unroll
    for (int i = 0; i < 4; i++) {
        const int gmb = m0 + wave_m * 64 + i * 16 + quad * 4;
        float a2x[4], a2y[4];
        if (RANK2) {
            #pragma unroll
            for (int r = 0; r < 4; r++) {
                a2x[r] = A2[(size_t)(gmb + r) * 2];
                a2y[r] = A2[(size_t)(gmb + r) * 2 + 1];
            }
        }
        float f0[4] = {0.f, 0.f, 0.f, 0.f};
        float f1[4] = {0.f, 0.f, 0.f, 0.f};
        #pragma unroll
        for (int j = 0; j < 4; j++) {
            const int gn = n0 + wave_n * 64 + j * 16 + fr;
            const bool nok = !EFMODE || (gn < 1027);
            const float bv = nok ? bias[gn] : 0.f;
            float w2a = 0.f, w2b = 0.f;
            if (RANK2) { w2a = W2r[gn]; w2b = W2r[512 + gn]; }
            float wcx = 0.f, wcy = 0.f;
            if (FUSEC) {
                const float2 wc = ((const float2*)Wc)[gn];
                wcx = wc.x; wcy = wc.y;
            }
            #pragma unroll
            for (int r = 0; r < 4; r++) {
                const int gm = gmb + r;
                float v = acc[i][j][r] + bv;
                if (RANK2) v += a2x[r] * w2a + a2y[r] * w2b;
                if (GELU) v = gelu_exact(v);
                if (EFMODE) {
                    if (gn < 2) EFC[(size_t)gm * 2 + gn] = v;
                    else if (gn < 1026)
                        EFB[(size_t)gm * 1024 + gn - 2] = __float2bfloat16(v);
                    if (nok) f0[r] += v * v;
                } else {
                    const __hip_bfloat16 h = __float2bfloat16(v);
                    const __hip_bfloat16 l =
                        __float2bfloat16(v - __bfloat162float(h));
                    Chi[(size_t)gm * 512 + gn] = h;
                    Clo[(size_t)gm * 512 + gn] = l;
                    if (FUSEC) { f0[r] += v * wcx; f1[r] += v * wcy; }
                }
            }
        }
        if (EFMODE || FUSEC) {
            #pragma unroll
            for (int r = 0; r < 4; r++) {
                float a = f0[r], b = f1[r];
                #pragma unroll
                for (int off = 1; off < 16; off <<= 1) {
                    a += __shfl_xor(a, off);
                    if (FUSEC) b += __shfl_xor(b, off);
                }
                if (fr == 0) {
                    if (FUSEC) {
                        atomicAdd(&CRD[(size_t)(gmb + r) * 2],     a);
                        atomicAdd(&CRD[(size_t)(gmb + r) * 2 + 1], b);
                    } else {
                        atomicAdd(&IMP[gmb + r], a);
                    }
                }
            }
        }
    }
}

// ===================== selection ============================================
__global__ __launch_bounds__(1024) void topk_kernel(
    const float* __restrict__ IMP, int* __restrict__ IDX)
{
    __shared__ float v[4096];
    __shared__ int   ix[4096];
    const int b = blockIdx.x, t = threadIdx.x;
    for (int i = t; i < 4096; i += 1024) {
        v[i] = sqrtf(IMP[b * 4096 + i]);   // IMP holds squared norms
        ix[i] = i;
    }
    __syncthreads();
    for (int k = 2; k <= 4096; k <<= 1) {
        for (int j = k >> 1; j > 0; j >>= 1) {
            for (int q = 0; q < 4; q++) {
                const int i = t + (q << 10);
                const int l = i ^ j;
                if (l > i) {
                    const float vi = v[i], vl = v[l];
                    const int   ii = ix[i], il = ix[l];
                    const bool after = (vi < vl) || (vi == vl && ii > il);
                    const bool dirAsc = ((i & k) == 0);
                    if (dirAsc ? after : !after) {
                        v[i] = vl; v[l] = vi; ix[i] = il; ix[l] = ii;
                    }
                }
            }
            __syncthreads();
        }
    }
    if (t < 512) IDX[b * 512 + t] = ix[t];
}

__global__ __launch_bounds__(256) void gather_kernel(
    const __hip_bfloat16* __restrict__ EFB, const float* __restrict__ EFC,
    const int* __restrict__ IDX,
    float* __restrict__ POS, __hip_bfloat16* __restrict__ ST)
{
    const int bn  = blockIdx.x;
    const int b   = bn >> 9;
    const int row = IDX[bn];
    const size_t src = (size_t)(b * 4096) + row;
    const int t = threadIdx.x;
    if (t < 2) POS[(size_t)bn * 2 + t] = EFC[src * 2 + t];
    const unsigned int* s = (const unsigned int*)(EFB + src * 1024);
    unsigned int* d = (unsigned int*)(ST + (size_t)bn * 1024);
    d[t]       = s[t];
    d[t + 256] = s[t + 256];
}

// ===================== weight transpose + fp32->bf16 (post-sel) =============
__global__ __launch_bounds__(256) void transpose_cvt_kernel(
    const float* __restrict__ in, __hip_bfloat16* __restrict__ out,
    int K, int N)
{
    __shared__ float tile[32][33];
    const int k0 = blockIdx.y * 32, n0 = blockIdx.x * 32;
    const int t = threadIdx.x;
    const int lr = t >> 5, lc = t & 31;
    #pragma unroll
    for (int p = 0; p < 4; p++) {
        const int r = p * 8 + lr;
        tile[r][lc] = in[(size_t)(k0 + r) * N + n0 + lc];
    }
    __syncthreads();
    #pragma unroll
    for (int p = 0; p < 4; p++) {
        const int r = p * 8 + lr;
        out[(size_t)(n0 + r) * K + k0 + lc] = __float2bfloat16(tile[lc][r]);
    }
}

__global__ __launch_bounds__(256) void transpose_proj_kernel(
    const __hip_bfloat16* __restrict__ in, __hip_bfloat16* __restrict__ out)
{
    __shared__ __hip_bfloat16 tile[32][33];
    const int b = blockIdx.z;
    const int n0 = blockIdx.y * 32, d0 = blockIdx.x * 32;
    const int t = threadIdx.x;
    const int lr = t >> 5, lc = t & 31;
    #pragma unroll
    for (int p = 0; p < 4; p++) {
        const int r = p * 8 + lr;
        tile[r][lc] = in[((size_t)b * 512 + n0 + r) * 512 + d0 + lc];
    }
    __syncthreads();
    #pragma unroll
    for (int p = 0; p < 4; p++) {
        const int r = p * 8 + lr;
        out[((size_t)b * 512 + d0 + r) * 512 + n0 + lc] = tile[lc][r];
    }
}

// ===================== bf16 MFMA GEMM (post-selection, dbuf) ================
template<bool GELU>
__global__ __launch_bounds__(256, 4) void gemm_post(
    const __hip_bfloat16* __restrict__ A,
    const __hip_bfloat16* __restrict__ BT,
    const float* __restrict__ bias,
    __hip_bfloat16* __restrict__ C,
    int N, int K)
{
    __shared__ __align__(16) __hip_bfloat16 As[2][128][32];
    __shared__ __align__(16) __hip_bfloat16 Bs[2][128][32];
    const int t = threadIdx.x;
    const int wave = t >> 6, lane = t & 63;
    const int wave_m = wave >> 1, wave_n = wave & 1;
    const int fr = lane & 15, quad = lane >> 4;
    const int gx = gridDim.x;
    const int nwg = gx * gridDim.y;
    int lid = blockIdx.y * gx + blockIdx.x;
    {
        const int chunk = nwg >> 3;
        lid = (lid & 7) * chunk + (lid >> 3);
    }
    const int m0 = (lid / gx) * 128;
    const int n0 = (lid % gx) * 128;
    const int srow = lane >> 2;
    const int skc  = (lane & 3) * 8;
    const int nsteps = K >> 5;

    f32x4 acc[4][4] = {};

    auto STAGE = [&](int buf, int step) {
        const int kk = step << 5;
        #pragma unroll
        for (int s = 0; s < 2; s++) {
            const int seg = wave * 2 + s;
            const int row = seg * 16 + srow;
            async_copy16(A  + (size_t)(m0 + row) * K + kk + skc,
                         &As[buf][seg * 16][0]);
            async_copy16(BT + (size_t)(n0 + row) * K + kk + skc,
                         &Bs[buf][seg * 16][0]);
        }
    };

    STAGE(0, 0);
    __syncthreads();
    int cur = 0;
    for (int step = 0; step < nsteps; ++step) {
        if (step + 1 < nsteps) STAGE(cur ^ 1, step + 1);
        bf16x8 af[4], bfv[4];
        #pragma unroll
        for (int i = 0; i < 4; i++)
            af[i] = *(const bf16x8*)&As[cur][wave_m * 64 + i * 16 + fr][quad * 8];
        #pragma unroll
        for (int j = 0; j < 4; j++)
            bfv[j] = *(const bf16x8*)&Bs[cur][wave_n * 64 + j * 16 + fr][quad * 8];
        #pragma unroll
        for (int i = 0; i < 4; i++)
            #pragma unroll
            for (int j = 0; j < 4; j++)
                acc[i][j] = __builtin_amdgcn_mfma_f32_16x16x32_bf16(
                    af[i], bfv[j], acc[i][j], 0, 0, 0);
        __syncthreads();
        cur ^= 1;
    }
    #pragma unroll
    for (int i = 0; i < 4; i++) {
        const int gm = m0 + wave_m * 64 + i * 16 + quad * 4;
        #pragma unroll
        for (int j = 0; j < 4; j++) {
            const int gn = n0 + wave_n * 64 + j * 16 + fr;
            const float bv = bias[gn];
            #pragma unroll
            for (int r = 0; r < 4; r++) {
                float v = acc[i][j][r] + bv;
                if (GELU) v = gelu_exact(v);
                C[(size_t)(gm + r) * N + gn] = __float2bfloat16(v);
            }
        }
    }
}

// ===================== fused attention output (bf16 MFMA) ===================
__global__ __launch_bounds__(256) void attn_mfma_kernel(
    const float* __restrict__ POS,
    const __hip_bfloat16* __restrict__ PROJT,
    float* __restrict__ OUT)
{
    __shared__ __align__(16) __hip_bfloat16 Bs[256][32];
    __shared__ float2 pos_s[512];
    __shared__ float srow_s[4][16];
    const int t = threadIdx.x;
    const int wave = t >> 6, lane = t & 63;
    const int fr = lane & 15, quad = lane >> 4;
    const int b  = blockIdx.z;
    const int g0 = blockIdx.x * 64;
    const int d0 = blockIdx.y * 256;

    {
        const float2* p = (const float2*)(POS + (size_t)b * 512 * 2);
        pos_s[t]       = p[t];
        pos_s[256 + t] = p[256 + t];
    }
    const int g = g0 + wave * 16 + fr;
    const bool gv = g < 10000;
    const float step = 2.0f / 99.0f;
    const int gi = gv ? (g / 100) : 0;
    const int gj = gv ? (g - gi * 100) : 0;
    const float gx = -1.f + step * (float)gi;
    const float gy = -1.f + step * (float)gj;

    f32x4 acc[16] = {};
    float wsum = 0.f;
    __syncthreads();

    for (int n0 = 0; n0 < 512; n0 += 32) {
        #pragma unroll
        for (int s = 0; s < 4; s++) {
            const int seg = wave * 4 + s;
            const __hip_bfloat16* gB = PROJT
                + ((size_t)b * 512 + d0 + seg * 16 + (lane >> 2)) * 512
                + n0 + (lane & 3) * 8;
            async_copy16(gB, &Bs[seg * 16][0]);
        }
        bf16x8 wf;
        float wl = 0.f;
        #pragma unroll
        for (int j = 0; j < 8; j++) {
            const int n = n0 + quad * 8 + j;
            const float2 pn = pos_s[n];
            const float dx = gx - pn.x, dy = gy - pn.y;
            const float w = gv ? __expf(-10.0f * (dx * dx + dy * dy)) : 0.f;
            const __hip_bfloat16 wb = __float2bfloat16(w);
            union { __hip_bfloat16 h; short s; } u; u.h = wb;
            wf[j] = u.s;
            wl += __bfloat162float(wb);
        }
        wsum += wl;
        __syncthreads();
        #pragma unroll
        for (int j = 0; j < 16; j++) {
            const bf16x8 bv = *(const bf16x8*)&Bs[j * 16 + fr][quad * 8];
            acc[j] = __builtin_amdgcn_mfma_f32_16x16x32_bf16(wf, bv, acc[j], 0, 0, 0);
        }
        __syncthreads();
    }
    wsum += __shfl_xor(wsum, 16);
    wsum += __shfl_xor(wsum, 32);
    if (lane < 16) srow_s[wave][lane] = wsum;
    __syncthreads();
    const int rbase = quad * 4;
    float inv[4];
    #pragma unroll
    for (int r = 0; r < 4; r++)
        inv[r] = 1.0f / (srow_s[wave][rbase + r] + 1e-8f);
    #pragma unroll
    for (int j = 0; j < 16; j++) {
        const int col = d0 + j * 16 + fr;
        #pragma unroll
        for (int r = 0; r < 4; r++) {
            const int gr = g0 + wave * 16 + rbase + r;
            if (gr < 10000)
                OUT[((size_t)b * 10000 + gr) * 512 + col] = acc[j][r] * inv[r];
        }
    }
}

// ===========================================================================
extern "C" void kernel_launch(void* const* d_in, const int* in_sizes, int n_in,
                              void* d_out, int out_size, void* d_ws, size_t ws_size,
                              hipStream_t stream)
{
    const float* x   = (const float*)d_in[0];
    const float* W1  = (const float*)d_in[1];
    const float* b1  = (const float*)d_in[2];
    const float* W2  = (const float*)d_in[3];
    const float* b2  = (const float*)d_in[4];
    const float* Wc  = (const float*)d_in[5];
    const float* bc  = (const float*)d_in[6];
    const float* We1 = (const float*)d_in[7];
    const float* be1 = (const float*)d_in[8];
    const float* We2 = (const float*)d_in[9];
    const float* be2 = (const float*)d_in[10];
    const float* Wo1 = (const float*)d_in[11];
    const float* bo1 = (const float*)d_in[12];
    const float* Wo2 = (const float*)d_in[13];
    const float* bo2 = (const float*)d_in[14];
    float* out = (float*)d_out;

    const size_t BS = 32768;
    const size_t ACT = BS * 512;             // elements per activation matrix
    // ---- workspace layout ----
    __hip_bfloat16* P0h = (__hip_bfloat16*)d_ws;        // 32 MB
    __hip_bfloat16* P0l = P0h + ACT;                    // 32 MB
    __hip_bfloat16* P1h = P0l + ACT;                    // 32 MB
    __hip_bfloat16* P1l = P1h + ACT;                    // 32 MB
    __hip_bfloat16* EFB = P1l + ACT;                    // 32768x1024 bf16
    float* EFC = (float*)(EFB + BS * 1024);             // 32768x2
    float* CRD = EFC + BS * 2;                          // 32768x2
    float* IMP = CRD + BS * 2;                          // 32768
    int*   IDX = (int*)(IMP + BS);                      // 4096
    float* POS = (float*)(IDX + 4096);                  // 4096x2
    __hip_bfloat16* W1Th = (__hip_bfloat16*)(POS + 4096 * 2);   // 512x512
    __hip_bfloat16* W1Tl = W1Th + 512 * 512;
    __hip_bfloat16* W2Th = W1Tl + 512 * 512;
    __hip_bfloat16* W2Tl = W2Th + 512 * 512;
    __hip_bfloat16* We1Th = W2Tl + 512 * 512;
    __hip_bfloat16* We1Tl = We1Th + 512 * 512;
    __hip_bfloat16* We2Th = We1Tl + 512 * 512;          // 1152x512
    __hip_bfloat16* We2Tl = We2Th + (size_t)1152 * 512;
    // post-selection pool aliases P0 (dead after h3 GEMM)
    __hip_bfloat16* ST    = P0h;                           // 4096x1024
    __hip_bfloat16* H4    = ST + (size_t)4096 * 1024;      // 4096x2048
    __hip_bfloat16* PROJ  = H4 + (size_t)4096 * 2048;      // 4096x512
    __hip_bfloat16* PROJT = PROJ + (size_t)4096 * 512;     // 8x512x512
    __hip_bfloat16* Wo1T  = PROJT + (size_t)4096 * 512;    // 2048x1024
    __hip_bfloat16* Wo2T  = Wo1T + (size_t)2048 * 1024;    // 512x2048

    dim3 blk(256);
    // ---- prep: split x, split+transpose pre-selection weights, init acc ----
    split_kernel<<<dim3(16384), blk, 0, stream>>>(x, P0h, P0l);
    transpose_split_kernel<<<dim3(16, 16), blk, 0, stream>>>(W1, W1Th, W1Tl, 512, 512);
    transpose_split_kernel<<<dim3(16, 16), blk, 0, stream>>>(W2, W2Th, W2Tl, 512, 512);
    transpose_split_kernel<<<dim3(16, 16), blk, 0, stream>>>(We1 + 2 * 512, We1Th, We1Tl, 512, 512);
    transpose_split_kernel<<<dim3(36, 16), blk, 0, stream>>>(We2, We2Th, We2Tl, 512, 1027);
    init_kernel<<<dim3(128), blk, 0, stream>>>(IMP, CRD, bc);
    // ---- pre-selection (bf16x3 MFMA, direct-global, barrier-free) ----
    // h1 = gelu(x@W1+b1) -> P1 pair
    gemm3k<true, false, false, false><<<dim3(4, 256), blk, 0, stream>>>(
        P0h, P0l, W1Th, W1Tl, b1, P1h, P1l,
        nullptr, nullptr, nullptr, nullptr, nullptr, nullptr, nullptr);
    // df = gelu(h1@W2+b2) -> P0 pair; coords fused (atomicAdd into CRD)
    gemm3k<true, false, false, true><<<dim3(4, 256), blk, 0, stream>>>(
        P1h, P1l, W2Th, W2Tl, b2, P0h, P0l,
        nullptr, nullptr, nullptr, nullptr, nullptr, CRD, Wc);
    // h3 = gelu(df@We1[2:] + coords@We1[:2] + be1) -> P1 pair
    gemm3k<true, true, false, false><<<dim3(4, 256), blk, 0, stream>>>(
        P0h, P0l, We1Th, We1Tl, be1, P1h, P1l,
        nullptr, nullptr, nullptr, CRD, We1, nullptr, nullptr);
    // ef = h3@We2+be2 -> EFB bf16 states + EFC coords + IMP (fused)
    gemm3k<false, false, true, false><<<dim3(9, 256), blk, 0, stream>>>(
        P1h, P1l, We2Th, We2Tl, be2, nullptr, nullptr,
        EFB, EFC, IMP, nullptr, nullptr, nullptr, nullptr);
    // ---- selection ----
    topk_kernel<<<dim3(8), dim3(1024), 0, stream>>>(IMP, IDX);
    // ---- post-selection weight prep (P0 pool free from here) ----
    transpose_cvt_kernel<<<dim3(64, 32), blk, 0, stream>>>(Wo1, Wo1T, 1024, 2048);
    transpose_cvt_kernel<<<dim3(16, 64), blk, 0, stream>>>(Wo2, Wo2T, 2048, 512);
    gather_kernel<<<dim3(4096), blk, 0, stream>>>(EFB, EFC, IDX, POS, ST);
    // ---- post-selection (bf16 MFMA, dbuf) ----
    gemm_post<true><<<dim3(16, 32), blk, 0, stream>>>(
        ST, Wo1T, bo1, H4, 2048, 1024);
    gemm_post<false><<<dim3(4, 32), blk, 0, stream>>>(
        H4, Wo2T, bo2, PROJ, 512, 2048);
    transpose_proj_kernel<<<dim3(16, 16, 8), blk, 0, stream>>>(PROJ, PROJT);
    attn_mfma_kernel<<<dim3(157, 2, 8), blk, 0, stream>>>(POS, PROJT, out);
}

// Round 4
// 941.871 us; speedup vs baseline: 1.2990x; 1.2990x over previous
//
#include <hip/hip_runtime.h>
#include <hip/hip_bf16.h>
#include <math.h>

// ---------------------------------------------------------------------------
// DFNPureModel round 7 (recombination):
//   gemm3k = round-3's proven loop structure (single-buffered LDS, 2 barriers
//   per K-step, 4-matrix staging, 48 MFMA per barrier, 32KB LDS) combined
//   with the two individually-verified orthogonal wins:
//     - m-chunked XCD swizzle (r6: FETCH 322MB -> 62MB)
//     - chunk-major LDS subtiles (r5: bank conflicts 14.2M -> 0)
//   No setprio (null on barrier-lockstep GEMM), no dbuf (regressed r5),
//   no direct-global (regressed r6).
//   Fusions kept (best-total r4/r5 set): coords fused into df epilogue,
//   squared importance fused into ef epilogue, ef states written bf16
//   (EFB) + coords fp32 (EFC), slim gather, sqrt inside top-k.
//   gemm_post / attn / transposes unchanged (round-4 versions).
// ---------------------------------------------------------------------------

typedef __attribute__((ext_vector_type(8))) short bf16x8;
typedef __attribute__((ext_vector_type(4))) float f32x4;

__device__ __forceinline__ float gelu_exact(float x) {
    return 0.5f * x * (1.0f + erff(x * 0.7071067811865476f));
}

__device__ __forceinline__ void async_copy16(const void* g, void* l) {
    __builtin_amdgcn_global_load_lds(
        (const __attribute__((address_space(1))) unsigned int*)g,
        (__attribute__((address_space(3))) unsigned int*)l, 16, 0, 0);
}

// ===================== elementwise fp32 -> (hi, lo) bf16 split ==============
__global__ __launch_bounds__(256) void split_kernel(
    const float* __restrict__ in,
    __hip_bfloat16* __restrict__ hi, __hip_bfloat16* __restrict__ lo)
{
    const int i4 = blockIdx.x * 256 + threadIdx.x;
    const float4 v = ((const float4*)in)[i4];
    __hip_bfloat16 h0 = __float2bfloat16(v.x);
    __hip_bfloat16 h1 = __float2bfloat16(v.y);
    __hip_bfloat16 h2 = __float2bfloat16(v.z);
    __hip_bfloat16 h3 = __float2bfloat16(v.w);
    __hip_bfloat16 l0 = __float2bfloat16(v.x - __bfloat162float(h0));
    __hip_bfloat16 l1 = __float2bfloat16(v.y - __bfloat162float(h1));
    __hip_bfloat16 l2 = __float2bfloat16(v.z - __bfloat162float(h2));
    __hip_bfloat16 l3 = __float2bfloat16(v.w - __bfloat162float(h3));
    union { __hip_bfloat16 h[4]; short4 s; } uh, ul;
    uh.h[0] = h0; uh.h[1] = h1; uh.h[2] = h2; uh.h[3] = h3;
    ul.h[0] = l0; ul.h[1] = l1; ul.h[2] = l2; ul.h[3] = l3;
    ((short4*)hi)[i4] = uh.s;
    ((short4*)lo)[i4] = ul.s;
}

// ============ W [K][N] fp32 -> WT hi/lo [Npad][K] bf16 (zero-padded) ========
__global__ __launch_bounds__(256) void transpose_split_kernel(
    const float* __restrict__ in,
    __hip_bfloat16* __restrict__ outH, __hip_bfloat16* __restrict__ outL,
    int K, int N)
{
    __shared__ float tile[32][33];
    const int k0 = blockIdx.y * 32, n0 = blockIdx.x * 32;
    const int t = threadIdx.x;
    const int lr = t >> 5, lc = t & 31;
    #pragma unroll
    for (int p = 0; p < 4; p++) {
        const int r = p * 8 + lr;
        const int n = n0 + lc;
        tile[r][lc] = (n < N) ? in[(size_t)(k0 + r) * N + n] : 0.f;
    }
    __syncthreads();
    #pragma unroll
    for (int p = 0; p < 4; p++) {
        const int r = p * 8 + lr;
        const float v = tile[lc][r];
        const __hip_bfloat16 h = __float2bfloat16(v);
        const __hip_bfloat16 l = __float2bfloat16(v - __bfloat162float(h));
        outH[(size_t)(n0 + r) * K + k0 + lc] = h;
        outL[(size_t)(n0 + r) * K + k0 + lc] = l;
    }
}

// ================= init: IMP = 0, CRD = bc (atomic accumulators) ============
__global__ __launch_bounds__(256) void init_kernel(
    float* __restrict__ IMP, float* __restrict__ CRD,
    const float* __restrict__ bc)
{
    const int t = blockIdx.x * 256 + threadIdx.x;   // 0..32767
    IMP[t] = 0.f;
    ((float2*)CRD)[t] = make_float2(bc[0], bc[1]);
}

// ===================== bf16x3 split-MFMA GEMM (pre-selection) ===============
// C = act(A @ BT^T + bias [+ rank2]); A = Ahi+Alo [M][512], BT = Bhi+Blo
// [Npad][512].  128x128 tile, 4 waves 2x2, 16x16x32 MFMA, 3 MFMA per frag,
// single-buffered LDS (32KB), 2 barriers per K-step, 48 MFMA per barrier.
// Chunk-major LDS: [seg 0..7][chunk 0..3][row 0..15][8 elems] -> staging
// lane map (row=lane&15, chunk=lane>>4) keeps global_load_lds linear-dest
// legal and makes fragment ds_read_b128 a linear 1KB/wave access (0 bank
// conflicts, verified r5).
// m-chunked XCD swizzle: XCD = L&7 owns contiguous m-range, n fastest ->
// B panel L2-resident per XCD, A-tile reused (FETCH 62MB, verified r6).
// EFMODE: states bf16 (cols 2..1025), coords fp32 (cols 0..1),
//         squared-importance atomicAdd (cols < 1027).
// FUSEC:  coords = C @ Wc accumulated via atomicAdd into CRD.
template<bool GELU, bool RANK2, bool EFMODE, bool FUSEC>
__global__ __launch_bounds__(256) void gemm3k(
    const __hip_bfloat16* __restrict__ Ahi, const __hip_bfloat16* __restrict__ Alo,
    const __hip_bfloat16* __restrict__ Bhi, const __hip_bfloat16* __restrict__ Blo,
    const float* __restrict__ bias,
    __hip_bfloat16* __restrict__ Chi, __hip_bfloat16* __restrict__ Clo,
    __hip_bfloat16* __restrict__ EFB, float* __restrict__ EFC,
    float* __restrict__ IMP,
    const float* __restrict__ A2, const float* __restrict__ W2r,
    float* __restrict__ CRD, const float* __restrict__ Wc)
{
    __shared__ __align__(16) __hip_bfloat16 AsH[4096];
    __shared__ __align__(16) __hip_bfloat16 AsL[4096];
    __shared__ __align__(16) __hip_bfloat16 BsH[4096];
    __shared__ __align__(16) __hip_bfloat16 BsL[4096];
    const int t = threadIdx.x;
    const int wave = t >> 6, lane = t & 63;
    const int wave_m = wave >> 1, wave_n = wave & 1;
    const int fr = lane & 15, quad = lane >> 4;
    // m-chunked XCD mapping (gridDim.y % 8 == 0): XCD x = L&7 owns m-blocks
    // [x*(gy/8) ...), n-fastest within.
    const int gx = gridDim.x;                 // n-blocks (4 or 9)
    const int L = blockIdx.y * gx + blockIdx.x;
    const int xcd = L & 7, kk_ = L >> 3;
    const int m_blk = xcd * (gridDim.y >> 3) + kk_ / gx;
    const int n_blk = kk_ % gx;
    const int m0 = m_blk * 128;
    const int n0 = n_blk * 128;
    const int lrow   = lane & 15;        // staging: row within 16-row seg
    const int lchunk = (lane >> 4) * 8;  // staging: col chunk (elements)

    f32x4 acc[4][4] = {};

    const int abase = wave_m * 2048 + quad * 128 + fr * 8;
    const int bbase = wave_n * 2048 + quad * 128 + fr * 8;

    for (int step = 0; step < 16; ++step) {
        const int kk = step << 5;
        #pragma unroll
        for (int s = 0; s < 2; s++) {
            const int seg = wave * 2 + s;
            const size_t ao = (size_t)(m0 + seg * 16 + lrow) * 512 + kk + lchunk;
            const size_t bo = (size_t)(n0 + seg * 16 + lrow) * 512 + kk + lchunk;
            async_copy16(Ahi + ao, &AsH[seg * 512]);
            async_copy16(Alo + ao, &AsL[seg * 512]);
            async_copy16(Bhi + bo, &BsH[seg * 512]);
            async_copy16(Blo + bo, &BsL[seg * 512]);
        }
        __syncthreads();
        bf16x8 ah[4], al[4], bh[4], bl[4];
        #pragma unroll
        for (int i = 0; i < 4; i++) {
            ah[i] = *(const bf16x8*)&AsH[abase + i * 512];
            al[i] = *(const bf16x8*)&AsL[abase + i * 512];
        }
        #pragma unroll
        for (int j = 0; j < 4; j++) {
            bh[j] = *(const bf16x8*)&BsH[bbase + j * 512];
            bl[j] = *(const bf16x8*)&BsL[bbase + j * 512];
        }
        #pragma unroll
        for (int i = 0; i < 4; i++)
            #pragma unroll
            for (int j = 0; j < 4; j++)
                acc[i][j] = __builtin_amdgcn_mfma_f32_16x16x32_bf16(
                    ah[i], bh[j], acc[i][j], 0, 0, 0);
        #pragma unroll
        for (int i = 0; i < 4; i++)
            #pragma unroll
            for (int j = 0; j < 4; j++)
                acc[i][j] = __builtin_amdgcn_mfma_f32_16x16x32_bf16(
                    ah[i], bl[j], acc[i][j], 0, 0, 0);
        #pragma unroll
        for (int i = 0; i < 4; i++)
            #pragma unroll
            for (int j = 0; j < 4; j++)
                acc[i][j] = __builtin_amdgcn_mfma_f32_16x16x32_bf16(
                    al[i], bh[j], acc[i][j], 0, 0, 0);
        __syncthreads();
    }

    // epilogue: row = m0 + wave_m*64 + i*16 + quad*4 + r,
    //           col = n0 + wave_n*64 + j*16 + fr
    #pragma unroll
    for (int i = 0; i < 4; i++) {
        const int gmb = m0 + wave_m * 64 + i * 16 + quad * 4;
        float a2x[4], a2y[4];
        if (RANK2) {
            #pragma unroll
            for (int r = 0; r < 4; r++) {
                a2x[r] = A2[(size_t)(gmb + r) * 2];
                a2y[r] = A2[(size_t)(gmb + r) * 2 + 1];
            }
        }
        float f0[4] = {0.f, 0.f, 0.f, 0.f};
        float f1[4] = {0.f, 0.f, 0.f, 0.f};
        #pragma unroll
        for (int j = 0; j < 4; j++) {
            const int gn = n0 + wave_n * 64 + j * 16 + fr;
            const bool nok = !EFMODE || (gn < 1027);
            const float bv = nok ? bias[gn] : 0.f;
            float w2a = 0.f, w2b = 0.f;
            if (RANK2) { w2a = W2r[gn]; w2b = W2r[512 + gn]; }
            float wcx = 0.f, wcy = 0.f;
            if (FUSEC) {
                const float2 wc = ((const float2*)Wc)[gn];
                wcx = wc.x; wcy = wc.y;
            }
            #pragma unroll
            for (int r = 0; r < 4; r++) {
                const int gm = gmb + r;
                float v = acc[i][j][r] + bv;
                if (RANK2) v += a2x[r] * w2a + a2y[r] * w2b;
                if (GELU) v = gelu_exact(v);
                if (EFMODE) {
                    if (gn < 2) EFC[(size_t)gm * 2 + gn] = v;
                    else if (gn < 1026)
                        EFB[(size_t)gm * 1024 + gn - 2] = __float2bfloat16(v);
                    if (nok) f0[r] += v * v;
                } else {
                    const __hip_bfloat16 h = __float2bfloat16(v);
                    const __hip_bfloat16 l =
                        __float2bfloat16(v - __bfloat162float(h));
                    Chi[(size_t)gm * 512 + gn] = h;
                    Clo[(size_t)gm * 512 + gn] = l;
                    if (FUSEC) { f0[r] += v * wcx; f1[r] += v * wcy; }
                }
            }
        }
        if (EFMODE || FUSEC) {
            #pragma unroll
            for (int r = 0; r < 4; r++) {
                float a = f0[r], b = f1[r];
                #pragma unroll
                for (int off = 1; off < 16; off <<= 1) {
                    a += __shfl_xor(a, off);
                    if (FUSEC) b += __shfl_xor(b, off);
                }
                if (fr == 0) {
                    if (FUSEC) {
                        atomicAdd(&CRD[(size_t)(gmb + r) * 2],     a);
                        atomicAdd(&CRD[(size_t)(gmb + r) * 2 + 1], b);
                    } else {
                        atomicAdd(&IMP[gmb + r], a);
                    }
                }
            }
        }
    }
}

// ===================== selection ============================================
__global__ __launch_bounds__(1024) void topk_kernel(
    const float* __restrict__ IMP, int* __restrict__ IDX)
{
    __shared__ float v[4096];
    __shared__ int   ix[4096];
    const int b = blockIdx.x, t = threadIdx.x;
    for (int i = t; i < 4096; i += 1024) {
        v[i] = sqrtf(IMP[b * 4096 + i]);   // IMP holds squared norms
        ix[i] = i;
    }
    __syncthreads();
    for (int k = 2; k <= 4096; k <<= 1) {
        for (int j = k >> 1; j > 0; j >>= 1) {
            for (int q = 0; q < 4; q++) {
                const int i = t + (q << 10);
                const int l = i ^ j;
                if (l > i) {
                    const float vi = v[i], vl = v[l];
                    const int   ii = ix[i], il = ix[l];
                    const bool after = (vi < vl) || (vi == vl && ii > il);
                    const bool dirAsc = ((i & k) == 0);
                    if (dirAsc ? after : !after) {
                        v[i] = vl; v[l] = vi; ix[i] = il; ix[l] = ii;
                    }
                }
            }
            __syncthreads();
        }
    }
    if (t < 512) IDX[b * 512 + t] = ix[t];
}

__global__ __launch_bounds__(256) void gather_kernel(
    const __hip_bfloat16* __restrict__ EFB, const float* __restrict__ EFC,
    const int* __restrict__ IDX,
    float* __restrict__ POS, __hip_bfloat16* __restrict__ ST)
{
    const int bn  = blockIdx.x;
    const int b   = bn >> 9;
    const int row = IDX[bn];
    const size_t src = (size_t)(b * 4096) + row;
    const int t = threadIdx.x;
    if (t < 2) POS[(size_t)bn * 2 + t] = EFC[src * 2 + t];
    const unsigned int* s = (const unsigned int*)(EFB + src * 1024);
    unsigned int* d = (unsigned int*)(ST + (size_t)bn * 1024);
    d[t]       = s[t];
    d[t + 256] = s[t + 256];
}

// ===================== weight transpose + fp32->bf16 (post-sel) =============
__global__ __launch_bounds__(256) void transpose_cvt_kernel(
    const float* __restrict__ in, __hip_bfloat16* __restrict__ out,
    int K, int N)
{
    __shared__ float tile[32][33];
    const int k0 = blockIdx.y * 32, n0 = blockIdx.x * 32;
    const int t = threadIdx.x;
    const int lr = t >> 5, lc = t & 31;
    #pragma unroll
    for (int p = 0; p < 4; p++) {
        const int r = p * 8 + lr;
        tile[r][lc] = in[(size_t)(k0 + r) * N + n0 + lc];
    }
    __syncthreads();
    #pragma unroll
    for (int p = 0; p < 4; p++) {
        const int r = p * 8 + lr;
        out[(size_t)(n0 + r) * K + k0 + lc] = __float2bfloat16(tile[lc][r]);
    }
}

__global__ __launch_bounds__(256) void transpose_proj_kernel(
    const __hip_bfloat16* __restrict__ in, __hip_bfloat16* __restrict__ out)
{
    __shared__ __hip_bfloat16 tile[32][33];
    const int b = blockIdx.z;
    const int n0 = blockIdx.y * 32, d0 = blockIdx.x * 32;
    const int t = threadIdx.x;
    const int lr = t >> 5, lc = t & 31;
    #pragma unroll
    for (int p = 0; p < 4; p++) {
        const int r = p * 8 + lr;
        tile[r][lc] = in[((size_t)b * 512 + n0 + r) * 512 + d0 + lc];
    }
    __syncthreads();
    #pragma unroll
    for (int p = 0; p < 4; p++) {
        const int r = p * 8 + lr;
        out[((size_t)b * 512 + d0 + r) * 512 + n0 + lc] = tile[lc][r];
    }
}

// ===================== bf16 MFMA GEMM (post-selection, dbuf) ================
template<bool GELU>
__global__ __launch_bounds__(256, 4) void gemm_post(
    const __hip_bfloat16* __restrict__ A,
    const __hip_bfloat16* __restrict__ BT,
    const float* __restrict__ bias,
    __hip_bfloat16* __restrict__ C,
    int N, int K)
{
    __shared__ __align__(16) __hip_bfloat16 As[2][128][32];
    __shared__ __align__(16) __hip_bfloat16 Bs[2][128][32];
    const int t = threadIdx.x;
    const int wave = t >> 6, lane = t & 63;
    const int wave_m = wave >> 1, wave_n = wave & 1;
    const int fr = lane & 15, quad = lane >> 4;
    const int gx = gridDim.x;
    const int nwg = gx * gridDim.y;
    int lid = blockIdx.y * gx + blockIdx.x;
    {
        const int chunk = nwg >> 3;
        lid = (lid & 7) * chunk + (lid >> 3);
    }
    const int m0 = (lid / gx) * 128;
    const int n0 = (lid % gx) * 128;
    const int srow = lane >> 2;
    const int skc  = (lane & 3) * 8;
    const int nsteps = K >> 5;

    f32x4 acc[4][4] = {};

    auto STAGE = [&](int buf, int step) {
        const int kk = step << 5;
        #pragma unroll
        for (int s = 0; s < 2; s++) {
            const int seg = wave * 2 + s;
            const int row = seg * 16 + srow;
            async_copy16(A  + (size_t)(m0 + row) * K + kk + skc,
                         &As[buf][seg * 16][0]);
            async_copy16(BT + (size_t)(n0 + row) * K + kk + skc,
                         &Bs[buf][seg * 16][0]);
        }
    };

    STAGE(0, 0);
    __syncthreads();
    int cur = 0;
    for (int step = 0; step < nsteps; ++step) {
        if (step + 1 < nsteps) STAGE(cur ^ 1, step + 1);
        bf16x8 af[4], bfv[4];
        #pragma unroll
        for (int i = 0; i < 4; i++)
            af[i] = *(const bf16x8*)&As[cur][wave_m * 64 + i * 16 + fr][quad * 8];
        #pragma unroll
        for (int j = 0; j < 4; j++)
            bfv[j] = *(const bf16x8*)&Bs[cur][wave_n * 64 + j * 16 + fr][quad * 8];
        #pragma unroll
        for (int i = 0; i < 4; i++)
            #pragma unroll
            for (int j = 0; j < 4; j++)
                acc[i][j] = __builtin_amdgcn_mfma_f32_16x16x32_bf16(
                    af[i], bfv[j], acc[i][j], 0, 0, 0);
        __syncthreads();
        cur ^= 1;
    }
    #pragma unroll
    for (int i = 0; i < 4; i++) {
        const int gm = m0 + wave_m * 64 + i * 16 + quad * 4;
        #pragma unroll
        for (int j = 0; j < 4; j++) {
            const int gn = n0 + wave_n * 64 + j * 16 + fr;
            const float bv = bias[gn];
            #pragma unroll
            for (int r = 0; r < 4; r++) {
                float v = acc[i][j][r] + bv;
                if (GELU) v = gelu_exact(v);
                C[(size_t)(gm + r) * N + gn] = __float2bfloat16(v);
            }
        }
    }
}

// ===================== fused attention output (bf16 MFMA) ===================
__global__ __launch_bounds__(256) void attn_mfma_kernel(
    const float* __restrict__ POS,
    const __hip_bfloat16* __restrict__ PROJT,
    float* __restrict__ OUT)
{
    __shared__ __align__(16) __hip_bfloat16 Bs[256][32];
    __shared__ float2 pos_s[512];
    __shared__ float srow_s[4][16];
    const int t = threadIdx.x;
    const int wave = t >> 6, lane = t & 63;
    const int fr = lane & 15, quad = lane >> 4;
    const int b  = blockIdx.z;
    const int g0 = blockIdx.x * 64;
    const int d0 = blockIdx.y * 256;

    {
        const float2* p = (const float2*)(POS + (size_t)b * 512 * 2);
        pos_s[t]       = p[t];
        pos_s[256 + t] = p[256 + t];
    }
    const int g = g0 + wave * 16 + fr;
    const bool gv = g < 10000;
    const float step = 2.0f / 99.0f;
    const int gi = gv ? (g / 100) : 0;
    const int gj = gv ? (g - gi * 100) : 0;
    const float gx = -1.f + step * (float)gi;
    const float gy = -1.f + step * (float)gj;

    f32x4 acc[16] = {};
    float wsum = 0.f;
    __syncthreads();

    for (int n0 = 0; n0 < 512; n0 += 32) {
        #pragma unroll
        for (int s = 0; s < 4; s++) {
            const int seg = wave * 4 + s;
            const __hip_bfloat16* gB = PROJT
                + ((size_t)b * 512 + d0 + seg * 16 + (lane >> 2)) * 512
                + n0 + (lane & 3) * 8;
            async_copy16(gB, &Bs[seg * 16][0]);
        }
        bf16x8 wf;
        float wl = 0.f;
        #pragma unroll
        for (int j = 0; j < 8; j++) {
            const int n = n0 + quad * 8 + j;
            const float2 pn = pos_s[n];
            const float dx = gx - pn.x, dy = gy - pn.y;
            const float w = gv ? __expf(-10.0f * (dx * dx + dy * dy)) : 0.f;
            const __hip_bfloat16 wb = __float2bfloat16(w);
            union { __hip_bfloat16 h; short s; } u; u.h = wb;
            wf[j] = u.s;
            wl += __bfloat162float(wb);
        }
        wsum += wl;
        __syncthreads();
        #pragma unroll
        for (int j = 0; j < 16; j++) {
            const bf16x8 bv = *(const bf16x8*)&Bs[j * 16 + fr][quad * 8];
            acc[j] = __builtin_amdgcn_mfma_f32_16x16x32_bf16(wf, bv, acc[j], 0, 0, 0);
        }
        __syncthreads();
    }
    wsum += __shfl_xor(wsum, 16);
    wsum += __shfl_xor(wsum, 32);
    if (lane < 16) srow_s[wave][lane] = wsum;
    __syncthreads();
    const int rbase = quad * 4;
    float inv[4];
    #pragma unroll
    for (int r = 0; r < 4; r++)
        inv[r] = 1.0f / (srow_s[wave][rbase + r] + 1e-8f);
    #pragma unroll
    for (int j = 0; j < 16; j++) {
        const int col = d0 + j * 16 + fr;
        #pragma unroll
        for (int r = 0; r < 4; r++) {
            const int gr = g0 + wave * 16 + rbase + r;
            if (gr < 10000)
                OUT[((size_t)b * 10000 + gr) * 512 + col] = acc[j][r] * inv[r];
        }
    }
}

// ===========================================================================
extern "C" void kernel_launch(void* const* d_in, const int* in_sizes, int n_in,
                              void* d_out, int out_size, void* d_ws, size_t ws_size,
                              hipStream_t stream)
{
    const float* x   = (const float*)d_in[0];
    const float* W1  = (const float*)d_in[1];
    const float* b1  = (const float*)d_in[2];
    const float* W2  = (const float*)d_in[3];
    const float* b2  = (const float*)d_in[4];
    const float* Wc  = (const float*)d_in[5];
    const float* bc  = (const float*)d_in[6];
    const float* We1 = (const float*)d_in[7];
    const float* be1 = (const float*)d_in[8];
    const float* We2 = (const float*)d_in[9];
    const float* be2 = (const float*)d_in[10];
    const float* Wo1 = (const float*)d_in[11];
    const float* bo1 = (const float*)d_in[12];
    const float* Wo2 = (const float*)d_in[13];
    const float* bo2 = (const float*)d_in[14];
    float* out = (float*)d_out;

    const size_t BS = 32768;
    const size_t ACT = BS * 512;             // elements per activation matrix
    // ---- workspace layout ----
    __hip_bfloat16* P0h = (__hip_bfloat16*)d_ws;        // 32 MB
    __hip_bfloat16* P0l = P0h + ACT;                    // 32 MB
    __hip_bfloat16* P1h = P0l + ACT;                    // 32 MB
    __hip_bfloat16* P1l = P1h + ACT;                    // 32 MB
    __hip_bfloat16* EFB = P1l + ACT;                    // 32768x1024 bf16
    float* EFC = (float*)(EFB + BS * 1024);             // 32768x2
    float* CRD = EFC + BS * 2;                          // 32768x2
    float* IMP = CRD + BS * 2;                          // 32768
    int*   IDX = (int*)(IMP + BS);                      // 4096
    float* POS = (float*)(IDX + 4096);                  // 4096x2
    __hip_bfloat16* W1Th = (__hip_bfloat16*)(POS + 4096 * 2);   // 512x512
    __hip_bfloat16* W1Tl = W1Th + 512 * 512;
    __hip_bfloat16* W2Th = W1Tl + 512 * 512;
    __hip_bfloat16* W2Tl = W2Th + 512 * 512;
    __hip_bfloat16* We1Th = W2Tl + 512 * 512;
    __hip_bfloat16* We1Tl = We1Th + 512 * 512;
    __hip_bfloat16* We2Th = We1Tl + 512 * 512;          // 1152x512
    __hip_bfloat16* We2Tl = We2Th + (size_t)1152 * 512;
    // post-selection pool aliases P0 (dead after h3 GEMM)
    __hip_bfloat16* ST    = P0h;                           // 4096x1024
    __hip_bfloat16* H4    = ST + (size_t)4096 * 1024;      // 4096x2048
    __hip_bfloat16* PROJ  = H4 + (size_t)4096 * 2048;      // 4096x512
    __hip_bfloat16* PROJT = PROJ + (size_t)4096 * 512;     // 8x512x512
    __hip_bfloat16* Wo1T  = PROJT + (size_t)4096 * 512;    // 2048x1024
    __hip_bfloat16* Wo2T  = Wo1T + (size_t)2048 * 1024;    // 512x2048

    dim3 blk(256);
    // ---- prep: split x, split+transpose pre-selection weights, init acc ----
    split_kernel<<<dim3(16384), blk, 0, stream>>>(x, P0h, P0l);
    transpose_split_kernel<<<dim3(16, 16), blk, 0, stream>>>(W1, W1Th, W1Tl, 512, 512);
    transpose_split_kernel<<<dim3(16, 16), blk, 0, stream>>>(W2, W2Th, W2Tl, 512, 512);
    transpose_split_kernel<<<dim3(16, 16), blk, 0, stream>>>(We1 + 2 * 512, We1Th, We1Tl, 512, 512);
    transpose_split_kernel<<<dim3(36, 16), blk, 0, stream>>>(We2, We2Th, We2Tl, 512, 1027);
    init_kernel<<<dim3(128), blk, 0, stream>>>(IMP, CRD, bc);
    // ---- pre-selection (bf16x3 MFMA, single-buffer + swizzle + chunk-major) --
    // h1 = gelu(x@W1+b1) -> P1 pair
    gemm3k<true, false, false, false><<<dim3(4, 256), blk, 0, stream>>>(
        P0h, P0l, W1Th, W1Tl, b1, P1h, P1l,
        nullptr, nullptr, nullptr, nullptr, nullptr, nullptr, nullptr);
    // df = gelu(h1@W2+b2) -> P0 pair; coords fused (atomicAdd into CRD)
    gemm3k<true, false, false, true><<<dim3(4, 256), blk, 0, stream>>>(
        P1h, P1l, W2Th, W2Tl, b2, P0h, P0l,
        nullptr, nullptr, nullptr, nullptr, nullptr, CRD, Wc);
    // h3 = gelu(df@We1[2:] + coords@We1[:2] + be1) -> P1 pair
    gemm3k<true, true, false, false><<<dim3(4, 256), blk, 0, stream>>>(
        P0h, P0l, We1Th, We1Tl, be1, P1h, P1l,
        nullptr, nullptr, nullptr, CRD, We1, nullptr, nullptr);
    // ef = h3@We2+be2 -> EFB bf16 states + EFC coords + IMP (fused)
    gemm3k<false, false, true, false><<<dim3(9, 256), blk, 0, stream>>>(
        P1h, P1l, We2Th, We2Tl, be2, nullptr, nullptr,
        EFB, EFC, IMP, nullptr, nullptr, nullptr, nullptr);
    // ---- selection ----
    topk_kernel<<<dim3(8), dim3(1024), 0, stream>>>(IMP, IDX);
    // ---- post-selection weight prep (P0 pool free from here) ----
    transpose_cvt_kernel<<<dim3(64, 32), blk, 0, stream>>>(Wo1, Wo1T, 1024, 2048);
    transpose_cvt_kernel<<<dim3(16, 64), blk, 0, stream>>>(Wo2, Wo2T, 2048, 512);
    gather_kernel<<<dim3(4096), blk, 0, stream>>>(EFB, EFC, IDX, POS, ST);
    // ---- post-selection (bf16 MFMA, dbuf) ----
    gemm_post<true><<<dim3(16, 32), blk, 0, stream>>>(
        ST, Wo1T, bo1, H4, 2048, 1024);
    gemm_post<false><<<dim3(4, 32), blk, 0, stream>>>(
        H4, Wo2T, bo2, PROJ, 512, 2048);
    transpose_proj_kernel<<<dim3(16, 16, 8), blk, 0, stream>>>(PROJ, PROJT);
    attn_mfma_kernel<<<dim3(157, 2, 8), blk, 0, stream>>>(POS, PROJT, out);
}

// Round 5
// 925.190 us; speedup vs baseline: 1.3225x; 1.0180x over previous
//
#include <hip/hip_runtime.h>
#include <hip/hip_bf16.h>
#include <math.h>

// ---------------------------------------------------------------------------
// DFNPureModel round 8 (attribution + consolidation):
//   All four pre-selection GEMMs use the r3-EXACT loop (the only variant
//   directly measured fastest: 162 us for ef): single-buffered LDS, 2
//   barriers per K-step, 4-matrix staging, row-major LDS [128][32] with
//   [quad*8] fragment reads, NO block swizzle. Epilogue-level fusions from
//   the best-total (898 us) r4 build are kept: coords fused into df,
//   squared importance fused into ef (fp32 EF output), sqrt inside top-k,
//   fp32-EF gather.
//   Each heavy kernel has a DISTINCT name (gemm_h1/df/h3/ef, gemm_o1/o2)
//   so rocprof top-5 finally attributes the time budget.
//   gemm_post / attn / transposes verbatim from the r4 build.
// ---------------------------------------------------------------------------

typedef __attribute__((ext_vector_type(8))) short bf16x8;
typedef __attribute__((ext_vector_type(4))) float f32x4;

__device__ __forceinline__ float gelu_exact(float x) {
    return 0.5f * x * (1.0f + erff(x * 0.7071067811865476f));
}

__device__ __forceinline__ void async_copy16(const void* g, void* l) {
    __builtin_amdgcn_global_load_lds(
        (const __attribute__((address_space(1))) unsigned int*)g,
        (__attribute__((address_space(3))) unsigned int*)l, 16, 0, 0);
}

// ===================== elementwise fp32 -> (hi, lo) bf16 split ==============
__global__ __launch_bounds__(256) void split_kernel(
    const float* __restrict__ in,
    __hip_bfloat16* __restrict__ hi, __hip_bfloat16* __restrict__ lo)
{
    const int i4 = blockIdx.x * 256 + threadIdx.x;
    const float4 v = ((const float4*)in)[i4];
    __hip_bfloat16 h0 = __float2bfloat16(v.x);
    __hip_bfloat16 h1 = __float2bfloat16(v.y);
    __hip_bfloat16 h2 = __float2bfloat16(v.z);
    __hip_bfloat16 h3 = __float2bfloat16(v.w);
    __hip_bfloat16 l0 = __float2bfloat16(v.x - __bfloat162float(h0));
    __hip_bfloat16 l1 = __float2bfloat16(v.y - __bfloat162float(h1));
    __hip_bfloat16 l2 = __float2bfloat16(v.z - __bfloat162float(h2));
    __hip_bfloat16 l3 = __float2bfloat16(v.w - __bfloat162float(h3));
    union { __hip_bfloat16 h[4]; short4 s; } uh, ul;
    uh.h[0] = h0; uh.h[1] = h1; uh.h[2] = h2; uh.h[3] = h3;
    ul.h[0] = l0; ul.h[1] = l1; ul.h[2] = l2; ul.h[3] = l3;
    ((short4*)hi)[i4] = uh.s;
    ((short4*)lo)[i4] = ul.s;
}

// ============ W [K][N] fp32 -> WT hi/lo [Npad][K] bf16 (zero-padded) ========
__global__ __launch_bounds__(256) void transpose_split_kernel(
    const float* __restrict__ in,
    __hip_bfloat16* __restrict__ outH, __hip_bfloat16* __restrict__ outL,
    int K, int N)
{
    __shared__ float tile[32][33];
    const int k0 = blockIdx.y * 32, n0 = blockIdx.x * 32;
    const int t = threadIdx.x;
    const int lr = t >> 5, lc = t & 31;
    #pragma unroll
    for (int p = 0; p < 4; p++) {
        const int r = p * 8 + lr;
        const int n = n0 + lc;
        tile[r][lc] = (n < N) ? in[(size_t)(k0 + r) * N + n] : 0.f;
    }
    __syncthreads();
    #pragma unroll
    for (int p = 0; p < 4; p++) {
        const int r = p * 8 + lr;
        const float v = tile[lc][r];
        const __hip_bfloat16 h = __float2bfloat16(v);
        const __hip_bfloat16 l = __float2bfloat16(v - __bfloat162float(h));
        outH[(size_t)(n0 + r) * K + k0 + lc] = h;
        outL[(size_t)(n0 + r) * K + k0 + lc] = l;
    }
}

// ================= init: IMP = 0, CRD = bc (atomic accumulators) ============
__global__ __launch_bounds__(256) void init_kernel(
    float* __restrict__ IMP, float* __restrict__ CRD,
    const float* __restrict__ bc)
{
    const int t = blockIdx.x * 256 + threadIdx.x;   // 0..32767
    IMP[t] = 0.f;
    ((float2*)CRD)[t] = make_float2(bc[0], bc[1]);
}

// ===================== bf16x3 split-MFMA GEMM body (r3-exact loop) ==========
// C = act(A @ BT^T + bias [+ rank2]); A = Ahi+Alo [M][512], BT = Bhi+Blo
// [Npad][512]. 128x128 tile, 4 waves 2x2, 16x16x32 MFMA, 3 MFMA per frag,
// single-buffered row-major LDS (32KB), 2 barriers per K-step, no swizzle.
// SPLIT:  C written as bf16 hi/lo pair (N=512).
// !SPLIT: C written fp32 to Cf (ldc), bounds-checked against N.
// FUSEC:  coords = C @ Wc atomicAdd'ed into CRD.
// FUSEI:  squared importance atomicAdd'ed into IMP (cols < N).
template<bool GELU, bool RANK2, bool SPLIT, bool FUSEC, bool FUSEI>
__device__ __forceinline__ void gemm3k_body(
    const __hip_bfloat16* __restrict__ Ahi, const __hip_bfloat16* __restrict__ Alo,
    const __hip_bfloat16* __restrict__ Bhi, const __hip_bfloat16* __restrict__ Blo,
    const float* __restrict__ bias,
    float* __restrict__ Cf, int ldc,
    __hip_bfloat16* __restrict__ Chi, __hip_bfloat16* __restrict__ Clo,
    int N,
    const float* __restrict__ A2, const float* __restrict__ W2r,
    float* __restrict__ CRD, const float* __restrict__ Wc,
    float* __restrict__ IMP)
{
    __shared__ __align__(16) __hip_bfloat16 AsH[128][32];
    __shared__ __align__(16) __hip_bfloat16 AsL[128][32];
    __shared__ __align__(16) __hip_bfloat16 BsH[128][32];
    __shared__ __align__(16) __hip_bfloat16 BsL[128][32];
    const int t = threadIdx.x;
    const int wave = t >> 6, lane = t & 63;
    const int wave_m = wave >> 1, wave_n = wave & 1;
    const int fr = lane & 15, quad = lane >> 4;
    const int m0 = blockIdx.y * 128;
    const int n0 = blockIdx.x * 128;
    const int srow = lane >> 2;
    const int skc  = (lane & 3) * 8;

    f32x4 acc[4][4] = {};

    for (int k0 = 0; k0 < 512; k0 += 32) {
        #pragma unroll
        for (int s = 0; s < 2; s++) {
            const int seg = wave * 2 + s;
            const int row = seg * 16 + srow;
            const size_t ao = (size_t)(m0 + row) * 512 + k0 + skc;
            const size_t bo = (size_t)(n0 + row) * 512 + k0 + skc;
            async_copy16(Ahi + ao, &AsH[seg * 16][0]);
            async_copy16(Alo + ao, &AsL[seg * 16][0]);
            async_copy16(Bhi + bo, &BsH[seg * 16][0]);
            async_copy16(Blo + bo, &BsL[seg * 16][0]);
        }
        __syncthreads();
        bf16x8 ah[4], al[4], bh[4], bl[4];
        #pragma unroll
        for (int i = 0; i < 4; i++) {
            ah[i] = *(const bf16x8*)&AsH[wave_m * 64 + i * 16 + fr][quad * 8];
            al[i] = *(const bf16x8*)&AsL[wave_m * 64 + i * 16 + fr][quad * 8];
        }
        #pragma unroll
        for (int j = 0; j < 4; j++) {
            bh[j] = *(const bf16x8*)&BsH[wave_n * 64 + j * 16 + fr][quad * 8];
            bl[j] = *(const bf16x8*)&BsL[wave_n * 64 + j * 16 + fr][quad * 8];
        }
        #pragma unroll
        for (int i = 0; i < 4; i++)
            #pragma unroll
            for (int j = 0; j < 4; j++)
                acc[i][j] = __builtin_amdgcn_mfma_f32_16x16x32_bf16(
                    ah[i], bh[j], acc[i][j], 0, 0, 0);
        #pragma unroll
        for (int i = 0; i < 4; i++)
            #pragma unroll
            for (int j = 0; j < 4; j++)
                acc[i][j] = __builtin_amdgcn_mfma_f32_16x16x32_bf16(
                    ah[i], bl[j], acc[i][j], 0, 0, 0);
        #pragma unroll
        for (int i = 0; i < 4; i++)
            #pragma unroll
            for (int j = 0; j < 4; j++)
                acc[i][j] = __builtin_amdgcn_mfma_f32_16x16x32_bf16(
                    al[i], bh[j], acc[i][j], 0, 0, 0);
        __syncthreads();
    }

    // epilogue: row = m0 + wave_m*64 + i*16 + quad*4 + r,
    //           col = n0 + wave_n*64 + j*16 + fr
    #pragma unroll
    for (int i = 0; i < 4; i++) {
        const int gmb = m0 + wave_m * 64 + i * 16 + quad * 4;
        float a2x[4], a2y[4];
        if (RANK2) {
            #pragma unroll
            for (int r = 0; r < 4; r++) {
                a2x[r] = A2[(size_t)(gmb + r) * 2];
                a2y[r] = A2[(size_t)(gmb + r) * 2 + 1];
            }
        }
        float f0[4] = {0.f, 0.f, 0.f, 0.f};
        float f1[4] = {0.f, 0.f, 0.f, 0.f};
        #pragma unroll
        for (int j = 0; j < 4; j++) {
            const int gn = n0 + wave_n * 64 + j * 16 + fr;
            const bool nok = SPLIT || (gn < N);
            const float bv = nok ? bias[gn] : 0.f;
            float w2a = 0.f, w2b = 0.f;
            if (RANK2) { w2a = W2r[gn]; w2b = W2r[512 + gn]; }
            float wcx = 0.f, wcy = 0.f;
            if (FUSEC) {
                const float2 wc = ((const float2*)Wc)[gn];
                wcx = wc.x; wcy = wc.y;
            }
            #pragma unroll
            for (int r = 0; r < 4; r++) {
                const int gm = gmb + r;
                float v = acc[i][j][r] + bv;
                if (RANK2) v += a2x[r] * w2a + a2y[r] * w2b;
                if (GELU) v = gelu_exact(v);
                if (SPLIT) {
                    const __hip_bfloat16 h = __float2bfloat16(v);
                    const __hip_bfloat16 l =
                        __float2bfloat16(v - __bfloat162float(h));
                    Chi[(size_t)gm * 512 + gn] = h;
                    Clo[(size_t)gm * 512 + gn] = l;
                } else if (nok) {
                    Cf[(size_t)gm * ldc + gn] = v;
                }
                if (FUSEC) { f0[r] += v * wcx; f1[r] += v * wcy; }
                if (FUSEI && nok) f0[r] += v * v;
            }
        }
        if (FUSEC || FUSEI) {
            #pragma unroll
            for (int r = 0; r < 4; r++) {
                float a = f0[r], b = f1[r];
                #pragma unroll
                for (int off = 1; off < 16; off <<= 1) {
                    a += __shfl_xor(a, off);
                    if (FUSEC) b += __shfl_xor(b, off);
                }
                if (fr == 0) {
                    if (FUSEC) {
                        atomicAdd(&CRD[(size_t)(gmb + r) * 2],     a);
                        atomicAdd(&CRD[(size_t)(gmb + r) * 2 + 1], b);
                    } else {
                        atomicAdd(&IMP[gmb + r], a);
                    }
                }
            }
        }
    }
}

// -------- named wrappers (distinct Kernel_Name for rocprof attribution) -----
__global__ __launch_bounds__(256) void gemm_h1(
    const __hip_bfloat16* __restrict__ Ahi, const __hip_bfloat16* __restrict__ Alo,
    const __hip_bfloat16* __restrict__ Bhi, const __hip_bfloat16* __restrict__ Blo,
    const float* __restrict__ bias,
    __hip_bfloat16* __restrict__ Chi, __hip_bfloat16* __restrict__ Clo)
{
    gemm3k_body<true, false, true, false, false>(
        Ahi, Alo, Bhi, Blo, bias, nullptr, 0, Chi, Clo, 512,
        nullptr, nullptr, nullptr, nullptr, nullptr);
}

__global__ __launch_bounds__(256) void gemm_df(
    const __hip_bfloat16* __restrict__ Ahi, const __hip_bfloat16* __restrict__ Alo,
    const __hip_bfloat16* __restrict__ Bhi, const __hip_bfloat16* __restrict__ Blo,
    const float* __restrict__ bias,
    __hip_bfloat16* __restrict__ Chi, __hip_bfloat16* __restrict__ Clo,
    float* __restrict__ CRD, const float* __restrict__ Wc)
{
    gemm3k_body<true, false, true, true, false>(
        Ahi, Alo, Bhi, Blo, bias, nullptr, 0, Chi, Clo, 512,
        nullptr, nullptr, CRD, Wc, nullptr);
}

__global__ __launch_bounds__(256) void gemm_h3(
    const __hip_bfloat16* __restrict__ Ahi, const __hip_bfloat16* __restrict__ Alo,
    const __hip_bfloat16* __restrict__ Bhi, const __hip_bfloat16* __restrict__ Blo,
    const float* __restrict__ bias,
    __hip_bfloat16* __restrict__ Chi, __hip_bfloat16* __restrict__ Clo,
    const float* __restrict__ A2, const float* __restrict__ W2r)
{
    gemm3k_body<true, true, true, false, false>(
        Ahi, Alo, Bhi, Blo, bias, nullptr, 0, Chi, Clo, 512,
        A2, W2r, nullptr, nullptr, nullptr);
}

__global__ __launch_bounds__(256) void gemm_ef(
    const __hip_bfloat16* __restrict__ Ahi, const __hip_bfloat16* __restrict__ Alo,
    const __hip_bfloat16* __restrict__ Bhi, const __hip_bfloat16* __restrict__ Blo,
    const float* __restrict__ bias,
    float* __restrict__ Cf, float* __restrict__ IMP)
{
    gemm3k_body<false, false, false, false, true>(
        Ahi, Alo, Bhi, Blo, bias, Cf, 1027, nullptr, nullptr, 1027,
        nullptr, nullptr, nullptr, nullptr, IMP);
}

// ===================== selection ============================================
__global__ __launch_bounds__(1024) void topk_kernel(
    const float* __restrict__ IMP, int* __restrict__ IDX)
{
    __shared__ float v[4096];
    __shared__ int   ix[4096];
    const int b = blockIdx.x, t = threadIdx.x;
    for (int i = t; i < 4096; i += 1024) {
        v[i] = sqrtf(IMP[b * 4096 + i]);   // IMP holds squared norms
        ix[i] = i;
    }
    __syncthreads();
    for (int k = 2; k <= 4096; k <<= 1) {
        for (int j = k >> 1; j > 0; j >>= 1) {
            for (int q = 0; q < 4; q++) {
                const int i = t + (q << 10);
                const int l = i ^ j;
                if (l > i) {
                    const float vi = v[i], vl = v[l];
                    const int   ii = ix[i], il = ix[l];
                    const bool after = (vi < vl) || (vi == vl && ii > il);
                    const bool dirAsc = ((i & k) == 0);
                    if (dirAsc ? after : !after) {
                        v[i] = vl; v[l] = vi; ix[i] = il; ix[l] = ii;
                    }
                }
            }
            __syncthreads();
        }
    }
    if (t < 512) IDX[b * 512 + t] = ix[t];
}

__global__ __launch_bounds__(256) void gather_kernel(
    const float* __restrict__ EF, const int* __restrict__ IDX,
    float* __restrict__ POS, __hip_bfloat16* __restrict__ ST)
{
    const int bn  = blockIdx.x;
    const int b   = bn >> 9;
    const int row = IDX[bn];
    const float* src = EF + ((size_t)(b * 4096) + row) * 1027;
    const int t = threadIdx.x;
    if (t < 2) POS[(size_t)bn * 2 + t] = src[t];
    __hip_bfloat16* dst = ST + (size_t)bn * 1024;
    for (int k = t; k < 1024; k += 256) dst[k] = __float2bfloat16(src[2 + k]);
}

// ===================== weight transpose + fp32->bf16 (post-sel) =============
__global__ __launch_bounds__(256) void transpose_cvt_kernel(
    const float* __restrict__ in, __hip_bfloat16* __restrict__ out,
    int K, int N)
{
    __shared__ float tile[32][33];
    const int k0 = blockIdx.y * 32, n0 = blockIdx.x * 32;
    const int t = threadIdx.x;
    const int lr = t >> 5, lc = t & 31;
    #pragma unroll
    for (int p = 0; p < 4; p++) {
        const int r = p * 8 + lr;
        tile[r][lc] = in[(size_t)(k0 + r) * N + n0 + lc];
    }
    __syncthreads();
    #pragma unroll
    for (int p = 0; p < 4; p++) {
        const int r = p * 8 + lr;
        out[(size_t)(n0 + r) * K + k0 + lc] = __float2bfloat16(tile[lc][r]);
    }
}

__global__ __launch_bounds__(256) void transpose_proj_kernel(
    const __hip_bfloat16* __restrict__ in, __hip_bfloat16* __restrict__ out)
{
    __shared__ __hip_bfloat16 tile[32][33];
    const int b = blockIdx.z;
    const int n0 = blockIdx.y * 32, d0 = blockIdx.x * 32;
    const int t = threadIdx.x;
    const int lr = t >> 5, lc = t & 31;
    #pragma unroll
    for (int p = 0; p < 4; p++) {
        const int r = p * 8 + lr;
        tile[r][lc] = in[((size_t)b * 512 + n0 + r) * 512 + d0 + lc];
    }
    __syncthreads();
    #pragma unroll
    for (int p = 0; p < 4; p++) {
        const int r = p * 8 + lr;
        out[((size_t)b * 512 + d0 + r) * 512 + n0 + lc] = tile[lc][r];
    }
}

// ===================== bf16 MFMA GEMM (post-selection, dbuf) ================
template<bool GELU>
__device__ __forceinline__ void gemm_post_body(
    const __hip_bfloat16* __restrict__ A,
    const __hip_bfloat16* __restrict__ BT,
    const float* __restrict__ bias,
    __hip_bfloat16* __restrict__ C,
    int N, int K)
{
    __shared__ __align__(16) __hip_bfloat16 As[2][128][32];
    __shared__ __align__(16) __hip_bfloat16 Bs[2][128][32];
    const int t = threadIdx.x;
    const int wave = t >> 6, lane = t & 63;
    const int wave_m = wave >> 1, wave_n = wave & 1;
    const int fr = lane & 15, quad = lane >> 4;
    const int gx = gridDim.x;
    const int nwg = gx * gridDim.y;
    int lid = blockIdx.y * gx + blockIdx.x;
    {
        const int chunk = nwg >> 3;
        lid = (lid & 7) * chunk + (lid >> 3);
    }
    const int m0 = (lid / gx) * 128;
    const int n0 = (lid % gx) * 128;
    const int srow = lane >> 2;
    const int skc  = (lane & 3) * 8;
    const int nsteps = K >> 5;

    f32x4 acc[4][4] = {};

    auto STAGE = [&](int buf, int step) {
        const int kk = step << 5;
        #pragma unroll
        for (int s = 0; s < 2; s++) {
            const int seg = wave * 2 + s;
            const int row = seg * 16 + srow;
            async_copy16(A  + (size_t)(m0 + row) * K + kk + skc,
                         &As[buf][seg * 16][0]);
            async_copy16(BT + (size_t)(n0 + row) * K + kk + skc,
                         &Bs[buf][seg * 16][0]);
        }
    };

    STAGE(0, 0);
    __syncthreads();
    int cur = 0;
    for (int step = 0; step < nsteps; ++step) {
        if (step + 1 < nsteps) STAGE(cur ^ 1, step + 1);
        bf16x8 af[4], bfv[4];
        #pragma unroll
        for (int i = 0; i < 4; i++)
            af[i] = *(const bf16x8*)&As[cur][wave_m * 64 + i * 16 + fr][quad * 8];
        #pragma unroll
        for (int j = 0; j < 4; j++)
            bfv[j] = *(const bf16x8*)&Bs[cur][wave_n * 64 + j * 16 + fr][quad * 8];
        #pragma unroll
        for (int i = 0; i < 4; i++)
            #pragma unroll
            for (int j = 0; j < 4; j++)
                acc[i][j] = __builtin_amdgcn_mfma_f32_16x16x32_bf16(
                    af[i], bfv[j], acc[i][j], 0, 0, 0);
        __syncthreads();
        cur ^= 1;
    }
    #pragma unroll
    for (int i = 0; i < 4; i++) {
        const int gm = m0 + wave_m * 64 + i * 16 + quad * 4;
        #pragma unroll
        for (int j = 0; j < 4; j++) {
            const int gn = n0 + wave_n * 64 + j * 16 + fr;
            const float bv = bias[gn];
            #pragma unroll
            for (int r = 0; r < 4; r++) {
                float v = acc[i][j][r] + bv;
                if (GELU) v = gelu_exact(v);
                C[(size_t)(gm + r) * N + gn] = __float2bfloat16(v);
            }
        }
    }
}

__global__ __launch_bounds__(256, 4) void gemm_o1(
    const __hip_bfloat16* __restrict__ A, const __hip_bfloat16* __restrict__ BT,
    const float* __restrict__ bias, __hip_bfloat16* __restrict__ C,
    int N, int K)
{
    gemm_post_body<true>(A, BT, bias, C, N, K);
}

__global__ __launch_bounds__(256, 4) void gemm_o2(
    const __hip_bfloat16* __restrict__ A, const __hip_bfloat16* __restrict__ BT,
    const float* __restrict__ bias, __hip_bfloat16* __restrict__ C,
    int N, int K)
{
    gemm_post_body<false>(A, BT, bias, C, N, K);
}

// ===================== fused attention output (bf16 MFMA) ===================
__global__ __launch_bounds__(256) void attn_mfma_kernel(
    const float* __restrict__ POS,
    const __hip_bfloat16* __restrict__ PROJT,
    float* __restrict__ OUT)
{
    __shared__ __align__(16) __hip_bfloat16 Bs[256][32];
    __shared__ float2 pos_s[512];
    __shared__ float srow_s[4][16];
    const int t = threadIdx.x;
    const int wave = t >> 6, lane = t & 63;
    const int fr = lane & 15, quad = lane >> 4;
    const int b  = blockIdx.z;
    const int g0 = blockIdx.x * 64;
    const int d0 = blockIdx.y * 256;

    {
        const float2* p = (const float2*)(POS + (size_t)b * 512 * 2);
        pos_s[t]       = p[t];
        pos_s[256 + t] = p[256 + t];
    }
    const int g = g0 + wave * 16 + fr;
    const bool gv = g < 10000;
    const float step = 2.0f / 99.0f;
    const int gi = gv ? (g / 100) : 0;
    const int gj = gv ? (g - gi * 100) : 0;
    const float gx = -1.f + step * (float)gi;
    const float gy = -1.f + step * (float)gj;

    f32x4 acc[16] = {};
    float wsum = 0.f;
    __syncthreads();

    for (int n0 = 0; n0 < 512; n0 += 32) {
        #pragma unroll
        for (int s = 0; s < 4; s++) {
            const int seg = wave * 4 + s;
            const __hip_bfloat16* gB = PROJT
                + ((size_t)b * 512 + d0 + seg * 16 + (lane >> 2)) * 512
                + n0 + (lane & 3) * 8;
            async_copy16(gB, &Bs[seg * 16][0]);
        }
        bf16x8 wf;
        float wl = 0.f;
        #pragma unroll
        for (int j = 0; j < 8; j++) {
            const int n = n0 + quad * 8 + j;
            const float2 pn = pos_s[n];
            const float dx = gx - pn.x, dy = gy - pn.y;
            const float w = gv ? __expf(-10.0f * (dx * dx + dy * dy)) : 0.f;
            const __hip_bfloat16 wb = __float2bfloat16(w);
            union { __hip_bfloat16 h; short s; } u; u.h = wb;
            wf[j] = u.s;
            wl += __bfloat162float(wb);
        }
        wsum += wl;
        __syncthreads();
        #pragma unroll
        for (int j = 0; j < 16; j++) {
            const bf16x8 bv = *(const bf16x8*)&Bs[j * 16 + fr][quad * 8];
            acc[j] = __builtin_amdgcn_mfma_f32_16x16x32_bf16(wf, bv, acc[j], 0, 0, 0);
        }
        __syncthreads();
    }
    wsum += __shfl_xor(wsum, 16);
    wsum += __shfl_xor(wsum, 32);
    if (lane < 16) srow_s[wave][lane] = wsum;
    __syncthreads();
    const int rbase = quad * 4;
    float inv[4];
    #pragma unroll
    for (int r = 0; r < 4; r++)
        inv[r] = 1.0f / (srow_s[wave][rbase + r] + 1e-8f);
    #pragma unroll
    for (int j = 0; j < 16; j++) {
        const int col = d0 + j * 16 + fr;
        #pragma unroll
        for (int r = 0; r < 4; r++) {
            const int gr = g0 + wave * 16 + rbase + r;
            if (gr < 10000)
                OUT[((size_t)b * 10000 + gr) * 512 + col] = acc[j][r] * inv[r];
        }
    }
}

// ===========================================================================
extern "C" void kernel_launch(void* const* d_in, const int* in_sizes, int n_in,
                              void* d_out, int out_size, void* d_ws, size_t ws_size,
                              hipStream_t stream)
{
    const float* x   = (const float*)d_in[0];
    const float* W1  = (const float*)d_in[1];
    const float* b1  = (const float*)d_in[2];
    const float* W2  = (const float*)d_in[3];
    const float* b2  = (const float*)d_in[4];
    const float* Wc  = (const float*)d_in[5];
    const float* bc  = (const float*)d_in[6];
    const float* We1 = (const float*)d_in[7];
    const float* be1 = (const float*)d_in[8];
    const float* We2 = (const float*)d_in[9];
    const float* be2 = (const float*)d_in[10];
    const float* Wo1 = (const float*)d_in[11];
    const float* bo1 = (const float*)d_in[12];
    const float* Wo2 = (const float*)d_in[13];
    const float* bo2 = (const float*)d_in[14];
    float* out = (float*)d_out;

    const size_t BS = 32768;
    const size_t ACT = BS * 512;             // elements per activation matrix
    // ---- workspace layout ----
    __hip_bfloat16* P0h = (__hip_bfloat16*)d_ws;        // 32 MB
    __hip_bfloat16* P0l = P0h + ACT;                    // 32 MB
    __hip_bfloat16* P1h = P0l + ACT;                    // 32 MB
    __hip_bfloat16* P1l = P1h + ACT;                    // 32 MB
    float* EF  = (float*)(P1l + ACT);                   // 32768x1027 fp32
    float* CRD = EF + BS * 1027;                        // 32768x2
    float* IMP = CRD + BS * 2;                          // 32768
    int*   IDX = (int*)(IMP + BS);                      // 4096
    float* POS = (float*)(IDX + 4096);                  // 4096x2
    __hip_bfloat16* W1Th = (__hip_bfloat16*)(POS + 4096 * 2);   // 512x512
    __hip_bfloat16* W1Tl = W1Th + 512 * 512;
    __hip_bfloat16* W2Th = W1Tl + 512 * 512;
    __hip_bfloat16* W2Tl = W2Th + 512 * 512;
    __hip_bfloat16* We1Th = W2Tl + 512 * 512;
    __hip_bfloat16* We1Tl = We1Th + 512 * 512;
    __hip_bfloat16* We2Th = We1Tl + 512 * 512;          // 1152x512
    __hip_bfloat16* We2Tl = We2Th + (size_t)1152 * 512;
    // post-selection pool aliases P0 (dead after h3 GEMM)
    __hip_bfloat16* ST    = P0h;                           // 4096x1024
    __hip_bfloat16* H4    = ST + (size_t)4096 * 1024;      // 4096x2048
    __hip_bfloat16* PROJ  = H4 + (size_t)4096 * 2048;      // 4096x512
    __hip_bfloat16* PROJT = PROJ + (size_t)4096 * 512;     // 8x512x512
    __hip_bfloat16* Wo1T  = PROJT + (size_t)4096 * 512;    // 2048x1024
    __hip_bfloat16* Wo2T  = Wo1T + (size_t)2048 * 1024;    // 512x2048

    dim3 blk(256);
    // ---- prep: split x, split+transpose pre-selection weights, init acc ----
    split_kernel<<<dim3(16384), blk, 0, stream>>>(x, P0h, P0l);
    transpose_split_kernel<<<dim3(16, 16), blk, 0, stream>>>(W1, W1Th, W1Tl, 512, 512);
    transpose_split_kernel<<<dim3(16, 16), blk, 0, stream>>>(W2, W2Th, W2Tl, 512, 512);
    transpose_split_kernel<<<dim3(16, 16), blk, 0, stream>>>(We1 + 2 * 512, We1Th, We1Tl, 512, 512);
    transpose_split_kernel<<<dim3(36, 16), blk, 0, stream>>>(We2, We2Th, We2Tl, 512, 1027);
    init_kernel<<<dim3(128), blk, 0, stream>>>(IMP, CRD, bc);
    // ---- pre-selection (bf16x3 MFMA, r3-exact loop, named kernels) ----
    // h1 = gelu(x@W1+b1) -> P1 pair
    gemm_h1<<<dim3(4, 256), blk, 0, stream>>>(
        P0h, P0l, W1Th, W1Tl, b1, P1h, P1l);
    // df = gelu(h1@W2+b2) -> P0 pair; coords fused (atomicAdd into CRD)
    gemm_df<<<dim3(4, 256), blk, 0, stream>>>(
        P1h, P1l, W2Th, W2Tl, b2, P0h, P0l, CRD, Wc);
    // h3 = gelu(df@We1[2:] + coords@We1[:2] + be1) -> P1 pair
    gemm_h3<<<dim3(4, 256), blk, 0, stream>>>(
        P0h, P0l, We1Th, We1Tl, be1, P1h, P1l, CRD, We1);
    // ef = h3@We2+be2 -> EF fp32 (N=1027); squared importance fused
    gemm_ef<<<dim3(9, 256), blk, 0, stream>>>(
        P1h, P1l, We2Th, We2Tl, be2, EF, IMP);
    // ---- selection ----
    topk_kernel<<<dim3(8), dim3(1024), 0, stream>>>(IMP, IDX);
    // ---- post-selection weight prep ----
    transpose_cvt_kernel<<<dim3(64, 32), blk, 0, stream>>>(Wo1, Wo1T, 1024, 2048);
    transpose_cvt_kernel<<<dim3(16, 64), blk, 0, stream>>>(Wo2, Wo2T, 2048, 512);
    gather_kernel<<<dim3(4096), blk, 0, stream>>>(EF, IDX, POS, ST);
    // ---- post-selection (bf16 MFMA, dbuf) ----
    gemm_o1<<<dim3(16, 32), blk, 0, stream>>>(ST, Wo1T, bo1, H4, 2048, 1024);
    gemm_o2<<<dim3(4, 32), blk, 0, stream>>>(H4, Wo2T, bo2, PROJ, 512, 2048);
    transpose_proj_kernel<<<dim3(16, 16, 8), blk, 0, stream>>>(PROJ, PROJT);
    attn_mfma_kernel<<<dim3(157, 2, 8), blk, 0, stream>>>(POS, PROJT, out);
}

// Round 6
// 908.009 us; speedup vs baseline: 1.3475x; 1.0189x over previous
//
#include <hip/hip_runtime.h>
#include <hip/hip_bf16.h>
#include <math.h>

// ---------------------------------------------------------------------------
// DFNPureModel round 9 (de-poison the fusion epilogue):
//   r8 attribution: top-5 = gemm_ef @209us; only delta vs r3's 162us is the
//   FUSEI atomic epilogue. All fused variants (r5/r7/r8) sit ~210 regardless
//   of loop structure -> the atomicAdd fusion epilogue is the ~47us cost.
//   Fix: keep the traffic-saving fusion but replace device-scope atomics
//   with NON-ATOMIC per-slice partial stores:
//     ef:  IMPP[18][32768]   (9 n-blocks x 2 wave_n), plain stores
//     df:  CRDP[8][32768][2] (4 n-blocks x 2 wave_n), plain stores
//   + tiny coords_sum kernel (CRD = bc + sum8 CRDP) before h3
//   + topk inline-sums the 18 IMPP slices before sqrt
//   + init_kernel removed (no atomic accumulators to zero).
//   GEMM loop stays r3-exact (single-buffer, 2 barriers/step, row-major LDS,
//   no swizzle - the only measured-fast configuration). Everything else
//   byte-identical to r8.
// ---------------------------------------------------------------------------

typedef __attribute__((ext_vector_type(8))) short bf16x8;
typedef __attribute__((ext_vector_type(4))) float f32x4;

__device__ __forceinline__ float gelu_exact(float x) {
    return 0.5f * x * (1.0f + erff(x * 0.7071067811865476f));
}

__device__ __forceinline__ void async_copy16(const void* g, void* l) {
    __builtin_amdgcn_global_load_lds(
        (const __attribute__((address_space(1))) unsigned int*)g,
        (__attribute__((address_space(3))) unsigned int*)l, 16, 0, 0);
}

// ===================== elementwise fp32 -> (hi, lo) bf16 split ==============
__global__ __launch_bounds__(256) void split_kernel(
    const float* __restrict__ in,
    __hip_bfloat16* __restrict__ hi, __hip_bfloat16* __restrict__ lo)
{
    const int i4 = blockIdx.x * 256 + threadIdx.x;
    const float4 v = ((const float4*)in)[i4];
    __hip_bfloat16 h0 = __float2bfloat16(v.x);
    __hip_bfloat16 h1 = __float2bfloat16(v.y);
    __hip_bfloat16 h2 = __float2bfloat16(v.z);
    __hip_bfloat16 h3 = __float2bfloat16(v.w);
    __hip_bfloat16 l0 = __float2bfloat16(v.x - __bfloat162float(h0));
    __hip_bfloat16 l1 = __float2bfloat16(v.y - __bfloat162float(h1));
    __hip_bfloat16 l2 = __float2bfloat16(v.z - __bfloat162float(h2));
    __hip_bfloat16 l3 = __float2bfloat16(v.w - __bfloat162float(h3));
    union { __hip_bfloat16 h[4]; short4 s; } uh, ul;
    uh.h[0] = h0; uh.h[1] = h1; uh.h[2] = h2; uh.h[3] = h3;
    ul.h[0] = l0; ul.h[1] = l1; ul.h[2] = l2; ul.h[3] = l3;
    ((short4*)hi)[i4] = uh.s;
    ((short4*)lo)[i4] = ul.s;
}

// ============ W [K][N] fp32 -> WT hi/lo [Npad][K] bf16 (zero-padded) ========
__global__ __launch_bounds__(256) void transpose_split_kernel(
    const float* __restrict__ in,
    __hip_bfloat16* __restrict__ outH, __hip_bfloat16* __restrict__ outL,
    int K, int N)
{
    __shared__ float tile[32][33];
    const int k0 = blockIdx.y * 32, n0 = blockIdx.x * 32;
    const int t = threadIdx.x;
    const int lr = t >> 5, lc = t & 31;
    #pragma unroll
    for (int p = 0; p < 4; p++) {
        const int r = p * 8 + lr;
        const int n = n0 + lc;
        tile[r][lc] = (n < N) ? in[(size_t)(k0 + r) * N + n] : 0.f;
    }
    __syncthreads();
    #pragma unroll
    for (int p = 0; p < 4; p++) {
        const int r = p * 8 + lr;
        const float v = tile[lc][r];
        const __hip_bfloat16 h = __float2bfloat16(v);
        const __hip_bfloat16 l = __float2bfloat16(v - __bfloat162float(h));
        outH[(size_t)(n0 + r) * K + k0 + lc] = h;
        outL[(size_t)(n0 + r) * K + k0 + lc] = l;
    }
}

// ===================== bf16x3 split-MFMA GEMM body (r3-exact loop) ==========
// C = act(A @ BT^T + bias [+ rank2]); A = Ahi+Alo [M][512], BT = Bhi+Blo
// [Npad][512]. 128x128 tile, 4 waves 2x2, 16x16x32 MFMA, 3 MFMA per frag,
// single-buffered row-major LDS (32KB), 2 barriers per K-step, no swizzle.
// SPLIT:  C written as bf16 hi/lo pair (N=512).
// !SPLIT: C written fp32 to Cf (ldc), bounds-checked against N.
// FUSEC:  per-slice coords partials -> CRDP[(n_blk*2+wave_n)][row][2] stores.
// FUSEI:  per-slice squared-importance partials -> IMPP[(n_blk*2+wave_n)][row].
template<bool GELU, bool RANK2, bool SPLIT, bool FUSEC, bool FUSEI>
__device__ __forceinline__ void gemm3k_body(
    const __hip_bfloat16* __restrict__ Ahi, const __hip_bfloat16* __restrict__ Alo,
    const __hip_bfloat16* __restrict__ Bhi, const __hip_bfloat16* __restrict__ Blo,
    const float* __restrict__ bias,
    float* __restrict__ Cf, int ldc,
    __hip_bfloat16* __restrict__ Chi, __hip_bfloat16* __restrict__ Clo,
    int N,
    const float* __restrict__ A2, const float* __restrict__ W2r,
    float* __restrict__ CRDP, const float* __restrict__ Wc,
    float* __restrict__ IMPP)
{
    __shared__ __align__(16) __hip_bfloat16 AsH[128][32];
    __shared__ __align__(16) __hip_bfloat16 AsL[128][32];
    __shared__ __align__(16) __hip_bfloat16 BsH[128][32];
    __shared__ __align__(16) __hip_bfloat16 BsL[128][32];
    const int t = threadIdx.x;
    const int wave = t >> 6, lane = t & 63;
    const int wave_m = wave >> 1, wave_n = wave & 1;
    const int fr = lane & 15, quad = lane >> 4;
    const int m0 = blockIdx.y * 128;
    const int n0 = blockIdx.x * 128;
    const int srow = lane >> 2;
    const int skc  = (lane & 3) * 8;

    f32x4 acc[4][4] = {};

    for (int k0 = 0; k0 < 512; k0 += 32) {
        #pragma unroll
        for (int s = 0; s < 2; s++) {
            const int seg = wave * 2 + s;
            const int row = seg * 16 + srow;
            const size_t ao = (size_t)(m0 + row) * 512 + k0 + skc;
            const size_t bo = (size_t)(n0 + row) * 512 + k0 + skc;
            async_copy16(Ahi + ao, &AsH[seg * 16][0]);
            async_copy16(Alo + ao, &AsL[seg * 16][0]);
            async_copy16(Bhi + bo, &BsH[seg * 16][0]);
            async_copy16(Blo + bo, &BsL[seg * 16][0]);
        }
        __syncthreads();
        bf16x8 ah[4], al[4], bh[4], bl[4];
        #pragma unroll
        for (int i = 0; i < 4; i++) {
            ah[i] = *(const bf16x8*)&AsH[wave_m * 64 + i * 16 + fr][quad * 8];
            al[i] = *(const bf16x8*)&AsL[wave_m * 64 + i * 16 + fr][quad * 8];
        }
        #pragma unroll
        for (int j = 0; j < 4; j++) {
            bh[j] = *(const bf16x8*)&BsH[wave_n * 64 + j * 16 + fr][quad * 8];
            bl[j] = *(const bf16x8*)&BsL[wave_n * 64 + j * 16 + fr][quad * 8];
        }
        #pragma unroll
        for (int i = 0; i < 4; i++)
            #pragma unroll
            for (int j = 0; j < 4; j++)
                acc[i][j] = __builtin_amdgcn_mfma_f32_16x16x32_bf16(
                    ah[i], bh[j], acc[i][j], 0, 0, 0);
        #pragma unroll
        for (int i = 0; i < 4; i++)
            #pragma unroll
            for (int j = 0; j < 4; j++)
                acc[i][j] = __builtin_amdgcn_mfma_f32_16x16x32_bf16(
                    ah[i], bl[j], acc[i][j], 0, 0, 0);
        #pragma unroll
        for (int i = 0; i < 4; i++)
            #pragma unroll
            for (int j = 0; j < 4; j++)
                acc[i][j] = __builtin_amdgcn_mfma_f32_16x16x32_bf16(
                    al[i], bh[j], acc[i][j], 0, 0, 0);
        __syncthreads();
    }

    // epilogue: row = m0 + wave_m*64 + i*16 + quad*4 + r,
    //           col = n0 + wave_n*64 + j*16 + fr
    const int slice = blockIdx.x * 2 + wave_n;
    #pragma unroll
    for (int i = 0; i < 4; i++) {
        const int gmb = m0 + wave_m * 64 + i * 16 + quad * 4;
        float a2x[4], a2y[4];
        if (RANK2) {
            #pragma unroll
            for (int r = 0; r < 4; r++) {
                a2x[r] = A2[(size_t)(gmb + r) * 2];
                a2y[r] = A2[(size_t)(gmb + r) * 2 + 1];
            }
        }
        float f0[4] = {0.f, 0.f, 0.f, 0.f};
        float f1[4] = {0.f, 0.f, 0.f, 0.f};
        #pragma unroll
        for (int j = 0; j < 4; j++) {
            const int gn = n0 + wave_n * 64 + j * 16 + fr;
            const bool nok = SPLIT || (gn < N);
            const float bv = nok ? bias[gn] : 0.f;
            float w2a = 0.f, w2b = 0.f;
            if (RANK2) { w2a = W2r[gn]; w2b = W2r[512 + gn]; }
            float wcx = 0.f, wcy = 0.f;
            if (FUSEC) {
                const float2 wc = ((const float2*)Wc)[gn];
                wcx = wc.x; wcy = wc.y;
            }
            #pragma unroll
            for (int r = 0; r < 4; r++) {
                const int gm = gmb + r;
                float v = acc[i][j][r] + bv;
                if (RANK2) v += a2x[r] * w2a + a2y[r] * w2b;
                if (GELU) v = gelu_exact(v);
                if (SPLIT) {
                    const __hip_bfloat16 h = __float2bfloat16(v);
                    const __hip_bfloat16 l =
                        __float2bfloat16(v - __bfloat162float(h));
                    Chi[(size_t)gm * 512 + gn] = h;
                    Clo[(size_t)gm * 512 + gn] = l;
                } else if (nok) {
                    Cf[(size_t)gm * ldc + gn] = v;
                }
                if (FUSEC) { f0[r] += v * wcx; f1[r] += v * wcy; }
                if (FUSEI && nok) f0[r] += v * v;
            }
        }
        if (FUSEC || FUSEI) {
            #pragma unroll
            for (int r = 0; r < 4; r++) {
                float a = f0[r], b = f1[r];
                #pragma unroll
                for (int off = 1; off < 16; off <<= 1) {
                    a += __shfl_xor(a, off);
                    if (FUSEC) b += __shfl_xor(b, off);
                }
                if (fr == 0) {
                    const int row = gmb + r;
                    if (FUSEC) {
                        CRDP[((size_t)slice * 32768 + row) * 2 + 0] = a;
                        CRDP[((size_t)slice * 32768 + row) * 2 + 1] = b;
                    } else {
                        IMPP[(size_t)slice * 32768 + row] = a;
                    }
                }
            }
        }
    }
}

// -------- named wrappers (distinct Kernel_Name for rocprof attribution) -----
__global__ __launch_bounds__(256) void gemm_h1(
    const __hip_bfloat16* __restrict__ Ahi, const __hip_bfloat16* __restrict__ Alo,
    const __hip_bfloat16* __restrict__ Bhi, const __hip_bfloat16* __restrict__ Blo,
    const float* __restrict__ bias,
    __hip_bfloat16* __restrict__ Chi, __hip_bfloat16* __restrict__ Clo)
{
    gemm3k_body<true, false, true, false, false>(
        Ahi, Alo, Bhi, Blo, bias, nullptr, 0, Chi, Clo, 512,
        nullptr, nullptr, nullptr, nullptr, nullptr);
}

__global__ __launch_bounds__(256) void gemm_df(
    const __hip_bfloat16* __restrict__ Ahi, const __hip_bfloat16* __restrict__ Alo,
    const __hip_bfloat16* __restrict__ Bhi, const __hip_bfloat16* __restrict__ Blo,
    const float* __restrict__ bias,
    __hip_bfloat16* __restrict__ Chi, __hip_bfloat16* __restrict__ Clo,
    float* __restrict__ CRDP, const float* __restrict__ Wc)
{
    gemm3k_body<true, false, true, true, false>(
        Ahi, Alo, Bhi, Blo, bias, nullptr, 0, Chi, Clo, 512,
        nullptr, nullptr, CRDP, Wc, nullptr);
}

__global__ __launch_bounds__(256) void gemm_h3(
    const __hip_bfloat16* __restrict__ Ahi, const __hip_bfloat16* __restrict__ Alo,
    const __hip_bfloat16* __restrict__ Bhi, const __hip_bfloat16* __restrict__ Blo,
    const float* __restrict__ bias,
    __hip_bfloat16* __restrict__ Chi, __hip_bfloat16* __restrict__ Clo,
    const float* __restrict__ A2, const float* __restrict__ W2r)
{
    gemm3k_body<true, true, true, false, false>(
        Ahi, Alo, Bhi, Blo, bias, nullptr, 0, Chi, Clo, 512,
        A2, W2r, nullptr, nullptr, nullptr);
}

__global__ __launch_bounds__(256) void gemm_ef(
    const __hip_bfloat16* __restrict__ Ahi, const __hip_bfloat16* __restrict__ Alo,
    const __hip_bfloat16* __restrict__ Bhi, const __hip_bfloat16* __restrict__ Blo,
    const float* __restrict__ bias,
    float* __restrict__ Cf, float* __restrict__ IMPP)
{
    gemm3k_body<false, false, false, false, true>(
        Ahi, Alo, Bhi, Blo, bias, Cf, 1027, nullptr, nullptr, 1027,
        nullptr, nullptr, nullptr, nullptr, IMPP);
}

// ============ coords finalize: CRD[row] = bc + sum of 8 CRDP slices =========
__global__ __launch_bounds__(256) void coords_sum_kernel(
    const float* __restrict__ CRDP, const float* __restrict__ bc,
    float* __restrict__ CRD)
{
    const int row = blockIdx.x * 256 + threadIdx.x;   // 0..32767
    float sx = bc[0], sy = bc[1];
    #pragma unroll
    for (int s = 0; s < 8; s++) {
        const float2 p = ((const float2*)CRDP)[(size_t)s * 32768 + row];
        sx += p.x; sy += p.y;
    }
    ((float2*)CRD)[row] = make_float2(sx, sy);
}

// ===================== selection ============================================
__global__ __launch_bounds__(1024) void topk_kernel(
    const float* __restrict__ IMPP, int* __restrict__ IDX)
{
    __shared__ float v[4096];
    __shared__ int   ix[4096];
    const int b = blockIdx.x, t = threadIdx.x;
    for (int i = t; i < 4096; i += 1024) {
        float s = 0.f;
        #pragma unroll
        for (int p = 0; p < 18; p++)
            s += IMPP[(size_t)p * 32768 + b * 4096 + i];
        v[i] = sqrtf(s);
        ix[i] = i;
    }
    __syncthreads();
    for (int k = 2; k <= 4096; k <<= 1) {
        for (int j = k >> 1; j > 0; j >>= 1) {
            for (int q = 0; q < 4; q++) {
                const int i = t + (q << 10);
                const int l = i ^ j;
                if (l > i) {
                    const float vi = v[i], vl = v[l];
                    const int   ii = ix[i], il = ix[l];
                    const bool after = (vi < vl) || (vi == vl && ii > il);
                    const bool dirAsc = ((i & k) == 0);
                    if (dirAsc ? after : !after) {
                        v[i] = vl; v[l] = vi; ix[i] = il; ix[l] = ii;
                    }
                }
            }
            __syncthreads();
        }
    }
    if (t < 512) IDX[b * 512 + t] = ix[t];
}

__global__ __launch_bounds__(256) void gather_kernel(
    const float* __restrict__ EF, const int* __restrict__ IDX,
    float* __restrict__ POS, __hip_bfloat16* __restrict__ ST)
{
    const int bn  = blockIdx.x;
    const int b   = bn >> 9;
    const int row = IDX[bn];
    const float* src = EF + ((size_t)(b * 4096) + row) * 1027;
    const int t = threadIdx.x;
    if (t < 2) POS[(size_t)bn * 2 + t] = src[t];
    __hip_bfloat16* dst = ST + (size_t)bn * 1024;
    for (int k = t; k < 1024; k += 256) dst[k] = __float2bfloat16(src[2 + k]);
}

// ===================== weight transpose + fp32->bf16 (post-sel) =============
__global__ __launch_bounds__(256) void transpose_cvt_kernel(
    const float* __restrict__ in, __hip_bfloat16* __restrict__ out,
    int K, int N)
{
    __shared__ float tile[32][33];
    const int k0 = blockIdx.y * 32, n0 = blockIdx.x * 32;
    const int t = threadIdx.x;
    const int lr = t >> 5, lc = t & 31;
    #pragma unroll
    for (int p = 0; p < 4; p++) {
        const int r = p * 8 + lr;
        tile[r][lc] = in[(size_t)(k0 + r) * N + n0 + lc];
    }
    __syncthreads();
    #pragma unroll
    for (int p = 0; p < 4; p++) {
        const int r = p * 8 + lr;
        out[(size_t)(n0 + r) * K + k0 + lc] = __float2bfloat16(tile[lc][r]);
    }
}

__global__ __launch_bounds__(256) void transpose_proj_kernel(
    const __hip_bfloat16* __restrict__ in, __hip_bfloat16* __restrict__ out)
{
    __shared__ __hip_bfloat16 tile[32][33];
    const int b = blockIdx.z;
    const int n0 = blockIdx.y * 32, d0 = blockIdx.x * 32;
    const int t = threadIdx.x;
    const int lr = t >> 5, lc = t & 31;
    #pragma unroll
    for (int p = 0; p < 4; p++) {
        const int r = p * 8 + lr;
        tile[r][lc] = in[((size_t)b * 512 + n0 + r) * 512 + d0 + lc];
    }
    __syncthreads();
    #pragma unroll
    for (int p = 0; p < 4; p++) {
        const int r = p * 8 + lr;
        out[((size_t)b * 512 + d0 + r) * 512 + n0 + lc] = tile[lc][r];
    }
}

// ===================== bf16 MFMA GEMM (post-selection, dbuf) ================
template<bool GELU>
__device__ __forceinline__ void gemm_post_body(
    const __hip_bfloat16* __restrict__ A,
    const __hip_bfloat16* __restrict__ BT,
    const float* __restrict__ bias,
    __hip_bfloat16* __restrict__ C,
    int N, int K)
{
    __shared__ __align__(16) __hip_bfloat16 As[2][128][32];
    __shared__ __align__(16) __hip_bfloat16 Bs[2][128][32];
    const int t = threadIdx.x;
    const int wave = t >> 6, lane = t & 63;
    const int wave_m = wave >> 1, wave_n = wave & 1;
    const int fr = lane & 15, quad = lane >> 4;
    const int gx = gridDim.x;
    const int nwg = gx * gridDim.y;
    int lid = blockIdx.y * gx + blockIdx.x;
    {
        const int chunk = nwg >> 3;
        lid = (lid & 7) * chunk + (lid >> 3);
    }
    const int m0 = (lid / gx) * 128;
    const int n0 = (lid % gx) * 128;
    const int srow = lane >> 2;
    const int skc  = (lane & 3) * 8;
    const int nsteps = K >> 5;

    f32x4 acc[4][4] = {};

    auto STAGE = [&](int buf, int step) {
        const int kk = step << 5;
        #pragma unroll
        for (int s = 0; s < 2; s++) {
            const int seg = wave * 2 + s;
            const int row = seg * 16 + srow;
            async_copy16(A  + (size_t)(m0 + row) * K + kk + skc,
                         &As[buf][seg * 16][0]);
            async_copy16(BT + (size_t)(n0 + row) * K + kk + skc,
                         &Bs[buf][seg * 16][0]);
        }
    };

    STAGE(0, 0);
    __syncthreads();
    int cur = 0;
    for (int step = 0; step < nsteps; ++step) {
        if (step + 1 < nsteps) STAGE(cur ^ 1, step + 1);
        bf16x8 af[4], bfv[4];
        #pragma unroll
        for (int i = 0; i < 4; i++)
            af[i] = *(const bf16x8*)&As[cur][wave_m * 64 + i * 16 + fr][quad * 8];
        #pragma unroll
        for (int j = 0; j < 4; j++)
            bfv[j] = *(const bf16x8*)&Bs[cur][wave_n * 64 + j * 16 + fr][quad * 8];
        #pragma unroll
        for (int i = 0; i < 4; i++)
            #pragma unroll
            for (int j = 0; j < 4; j++)
                acc[i][j] = __builtin_amdgcn_mfma_f32_16x16x32_bf16(
                    af[i], bfv[j], acc[i][j], 0, 0, 0);
        __syncthreads();
        cur ^= 1;
    }
    #pragma unroll
    for (int i = 0; i < 4; i++) {
        const int gm = m0 + wave_m * 64 + i * 16 + quad * 4;
        #pragma unroll
        for (int j = 0; j < 4; j++) {
            const int gn = n0 + wave_n * 64 + j * 16 + fr;
            const float bv = bias[gn];
            #pragma unroll
            for (int r = 0; r < 4; r++) {
                float v = acc[i][j][r] + bv;
                if (GELU) v = gelu_exact(v);
                C[(size_t)(gm + r) * N + gn] = __float2bfloat16(v);
            }
        }
    }
}

__global__ __launch_bounds__(256, 4) void gemm_o1(
    const __hip_bfloat16* __restrict__ A, const __hip_bfloat16* __restrict__ BT,
    const float* __restrict__ bias, __hip_bfloat16* __restrict__ C,
    int N, int K)
{
    gemm_post_body<true>(A, BT, bias, C, N, K);
}

__global__ __launch_bounds__(256, 4) void gemm_o2(
    const __hip_bfloat16* __restrict__ A, const __hip_bfloat16* __restrict__ BT,
    const float* __restrict__ bias, __hip_bfloat16* __restrict__ C,
    int N, int K)
{
    gemm_post_body<false>(A, BT, bias, C, N, K);
}

// ===================== fused attention output (bf16 MFMA) ===================
__global__ __launch_bounds__(256) void attn_mfma_kernel(
    const float* __restrict__ POS,
    const __hip_bfloat16* __restrict__ PROJT,
    float* __restrict__ OUT)
{
    __shared__ __align__(16) __hip_bfloat16 Bs[256][32];
    __shared__ float2 pos_s[512];
    __shared__ float srow_s[4][16];
    const int t = threadIdx.x;
    const int wave = t >> 6, lane = t & 63;
    const int fr = lane & 15, quad = lane >> 4;
    const int b  = blockIdx.z;
    const int g0 = blockIdx.x * 64;
    const int d0 = blockIdx.y * 256;

    {
        const float2* p = (const float2*)(POS + (size_t)b * 512 * 2);
        pos_s[t]       = p[t];
        pos_s[256 + t] = p[256 + t];
    }
    const int g = g0 + wave * 16 + fr;
    const bool gv = g < 10000;
    const float step = 2.0f / 99.0f;
    const int gi = gv ? (g / 100) : 0;
    const int gj = gv ? (g - gi * 100) : 0;
    const float gx = -1.f + step * (float)gi;
    const float gy = -1.f + step * (float)gj;

    f32x4 acc[16] = {};
    float wsum = 0.f;
    __syncthreads();

    for (int n0 = 0; n0 < 512; n0 += 32) {
        #pragma unroll
        for (int s = 0; s < 4; s++) {
            const int seg = wave * 4 + s;
            const __hip_bfloat16* gB = PROJT
                + ((size_t)b * 512 + d0 + seg * 16 + (lane >> 2)) * 512
                + n0 + (lane & 3) * 8;
            async_copy16(gB, &Bs[seg * 16][0]);
        }
        bf16x8 wf;
        float wl = 0.f;
        #pragma unroll
        for (int j = 0; j < 8; j++) {
            const int n = n0 + quad * 8 + j;
            const float2 pn = pos_s[n];
            const float dx = gx - pn.x, dy = gy - pn.y;
            const float w = gv ? __expf(-10.0f * (dx * dx + dy * dy)) : 0.f;
            const __hip_bfloat16 wb = __float2bfloat16(w);
            union { __hip_bfloat16 h; short s; } u; u.h = wb;
            wf[j] = u.s;
            wl += __bfloat162float(wb);
        }
        wsum += wl;
        __syncthreads();
        #pragma unroll
        for (int j = 0; j < 16; j++) {
            const bf16x8 bv = *(const bf16x8*)&Bs[j * 16 + fr][quad * 8];
            acc[j] = __builtin_amdgcn_mfma_f32_16x16x32_bf16(wf, bv, acc[j], 0, 0, 0);
        }
        __syncthreads();
    }
    wsum += __shfl_xor(wsum, 16);
    wsum += __shfl_xor(wsum, 32);
    if (lane < 16) srow_s[wave][lane] = wsum;
    __syncthreads();
    const int rbase = quad * 4;
    float inv[4];
    #pragma unroll
    for (int r = 0; r < 4; r++)
        inv[r] = 1.0f / (srow_s[wave][rbase + r] + 1e-8f);
    #pragma unroll
    for (int j = 0; j < 16; j++) {
        const int col = d0 + j * 16 + fr;
        #pragma unroll
        for (int r = 0; r < 4; r++) {
            const int gr = g0 + wave * 16 + rbase + r;
            if (gr < 10000)
                OUT[((size_t)b * 10000 + gr) * 512 + col] = acc[j][r] * inv[r];
        }
    }
}

// ===========================================================================
extern "C" void kernel_launch(void* const* d_in, const int* in_sizes, int n_in,
                              void* d_out, int out_size, void* d_ws, size_t ws_size,
                              hipStream_t stream)
{
    const float* x   = (const float*)d_in[0];
    const float* W1  = (const float*)d_in[1];
    const float* b1  = (const float*)d_in[2];
    const float* W2  = (const float*)d_in[3];
    const float* b2  = (const float*)d_in[4];
    const float* Wc  = (const float*)d_in[5];
    const float* bc  = (const float*)d_in[6];
    const float* We1 = (const float*)d_in[7];
    const float* be1 = (const float*)d_in[8];
    const float* We2 = (const float*)d_in[9];
    const float* be2 = (const float*)d_in[10];
    const float* Wo1 = (const float*)d_in[11];
    const float* bo1 = (const float*)d_in[12];
    const float* Wo2 = (const float*)d_in[13];
    const float* bo2 = (const float*)d_in[14];
    float* out = (float*)d_out;

    const size_t BS = 32768;
    const size_t ACT = BS * 512;             // elements per activation matrix
    // ---- workspace layout ----
    __hip_bfloat16* P0h = (__hip_bfloat16*)d_ws;        // 32 MB
    __hip_bfloat16* P0l = P0h + ACT;                    // 32 MB
    __hip_bfloat16* P1h = P0l + ACT;                    // 32 MB
    __hip_bfloat16* P1l = P1h + ACT;                    // 32 MB
    float* EF   = (float*)(P1l + ACT);                  // 32768x1027 fp32
    float* CRD  = EF + BS * 1027;                       // 32768x2
    float* CRDP = CRD + BS * 2;                         // 8 x 32768 x 2
    float* IMPP = CRDP + 8 * BS * 2;                    // 18 x 32768
    int*   IDX  = (int*)(IMPP + 18 * BS);               // 4096
    float* POS  = (float*)(IDX + 4096);                 // 4096x2
    __hip_bfloat16* W1Th = (__hip_bfloat16*)(POS + 4096 * 2);   // 512x512
    __hip_bfloat16* W1Tl = W1Th + 512 * 512;
    __hip_bfloat16* W2Th = W1Tl + 512 * 512;
    __hip_bfloat16* W2Tl = W2Th + 512 * 512;
    __hip_bfloat16* We1Th = W2Tl + 512 * 512;
    __hip_bfloat16* We1Tl = We1Th + 512 * 512;
    __hip_bfloat16* We2Th = We1Tl + 512 * 512;          // 1152x512
    __hip_bfloat16* We2Tl = We2Th + (size_t)1152 * 512;
    // post-selection pool aliases P0 (dead after h3 GEMM)
    __hip_bfloat16* ST    = P0h;                           // 4096x1024
    __hip_bfloat16* H4    = ST + (size_t)4096 * 1024;      // 4096x2048
    __hip_bfloat16* PROJ  = H4 + (size_t)4096 * 2048;      // 4096x512
    __hip_bfloat16* PROJT = PROJ + (size_t)4096 * 512;     // 8x512x512
    __hip_bfloat16* Wo1T  = PROJT + (size_t)4096 * 512;    // 2048x1024
    __hip_bfloat16* Wo2T  = Wo1T + (size_t)2048 * 1024;    // 512x2048

    dim3 blk(256);
    // ---- prep: split x, split+transpose pre-selection weights ----
    split_kernel<<<dim3(16384), blk, 0, stream>>>(x, P0h, P0l);
    transpose_split_kernel<<<dim3(16, 16), blk, 0, stream>>>(W1, W1Th, W1Tl, 512, 512);
    transpose_split_kernel<<<dim3(16, 16), blk, 0, stream>>>(W2, W2Th, W2Tl, 512, 512);
    transpose_split_kernel<<<dim3(16, 16), blk, 0, stream>>>(We1 + 2 * 512, We1Th, We1Tl, 512, 512);
    transpose_split_kernel<<<dim3(36, 16), blk, 0, stream>>>(We2, We2Th, We2Tl, 512, 1027);
    // ---- pre-selection (bf16x3 MFMA, r3-exact loop, named kernels) ----
    // h1 = gelu(x@W1+b1) -> P1 pair
    gemm_h1<<<dim3(4, 256), blk, 0, stream>>>(
        P0h, P0l, W1Th, W1Tl, b1, P1h, P1l);
    // df = gelu(h1@W2+b2) -> P0 pair; coords partials -> CRDP (plain stores)
    gemm_df<<<dim3(4, 256), blk, 0, stream>>>(
        P1h, P1l, W2Th, W2Tl, b2, P0h, P0l, CRDP, Wc);
    // CRD = bc + sum of CRDP slices
    coords_sum_kernel<<<dim3(128), blk, 0, stream>>>(CRDP, bc, CRD);
    // h3 = gelu(df@We1[2:] + coords@We1[:2] + be1) -> P1 pair
    gemm_h3<<<dim3(4, 256), blk, 0, stream>>>(
        P0h, P0l, We1Th, We1Tl, be1, P1h, P1l, CRD, We1);
    // ef = h3@We2+be2 -> EF fp32 (N=1027); importance partials -> IMPP
    gemm_ef<<<dim3(9, 256), blk, 0, stream>>>(
        P1h, P1l, We2Th, We2Tl, be2, EF, IMPP);
    // ---- selection (topk sums IMPP slices + sqrt) ----
    topk_kernel<<<dim3(8), dim3(1024), 0, stream>>>(IMPP, IDX);
    // ---- post-selection weight prep ----
    transpose_cvt_kernel<<<dim3(64, 32), blk, 0, stream>>>(Wo1, Wo1T, 1024, 2048);
    transpose_cvt_kernel<<<dim3(16, 64), blk, 0, stream>>>(Wo2, Wo2T, 2048, 512);
    gather_kernel<<<dim3(4096), blk, 0, stream>>>(EF, IDX, POS, ST);
    // ---- post-selection (bf16 MFMA, dbuf) ----
    gemm_o1<<<dim3(16, 32), blk, 0, stream>>>(ST, Wo1T, bo1, H4, 2048, 1024);
    gemm_o2<<<dim3(4, 32), blk, 0, stream>>>(H4, Wo2T, bo2, PROJ, 512, 2048);
    transpose_proj_kernel<<<dim3(16, 16, 8), blk, 0, stream>>>(PROJ, PROJT);
    attn_mfma_kernel<<<dim3(157, 2, 8), blk, 0, stream>>>(POS, PROJT, out);
}

// Round 7
// 899.314 us; speedup vs baseline: 1.3605x; 1.0097x over previous
//
#include <hip/hip_runtime.h>
#include <hip/hip_bf16.h>
#include <math.h>

// ---------------------------------------------------------------------------
// DFNPureModel round 10 (clean isolation: r0-exact GEMMs + XCD swizzle):
//   r9 lesson: the fusion epilogue itself costs ~40us (MfmaUtil 30->24 on an
//   identical loop) regardless of atomics -> ALL fusions removed; ef/df/h1/h3
//   revert to the r0-attested unfused forms (ef 162us attested), with
//   separate coords_kernel + importance_kernel (r0-attested).
//   ONE new variable: bijective m-chunked XCD swizzle (attested FETCH
//   322->62..83MB in r6/r7, but never tested without the fusion confound):
//     xcd = L&7 owns a contiguous m-range, n fastest within
//     -> A panel + B panel L2-resident per XCD.
//   Decision rule: ef <=130us -> HBM-pattern theory confirmed;
//                  ef >=150us w/ FETCH<100MB -> latency-bound confirmed,
//                  next round attacks occupancy/pipeline depth.
//   Post-selection path (gemm_o1/o2 dbuf+swizzle, transpose_proj, attn)
//   unchanged from r9. Named kernels kept for attribution.
// ---------------------------------------------------------------------------

typedef __attribute__((ext_vector_type(8))) short bf16x8;
typedef __attribute__((ext_vector_type(4))) float f32x4;

__device__ __forceinline__ float gelu_exact(float x) {
    return 0.5f * x * (1.0f + erff(x * 0.7071067811865476f));
}

__device__ __forceinline__ void async_copy16(const void* g, void* l) {
    __builtin_amdgcn_global_load_lds(
        (const __attribute__((address_space(1))) unsigned int*)g,
        (__attribute__((address_space(3))) unsigned int*)l, 16, 0, 0);
}

// ===================== elementwise fp32 -> (hi, lo) bf16 split ==============
__global__ __launch_bounds__(256) void split_kernel(
    const float* __restrict__ in,
    __hip_bfloat16* __restrict__ hi, __hip_bfloat16* __restrict__ lo)
{
    const int i4 = blockIdx.x * 256 + threadIdx.x;
    const float4 v = ((const float4*)in)[i4];
    __hip_bfloat16 h0 = __float2bfloat16(v.x);
    __hip_bfloat16 h1 = __float2bfloat16(v.y);
    __hip_bfloat16 h2 = __float2bfloat16(v.z);
    __hip_bfloat16 h3 = __float2bfloat16(v.w);
    __hip_bfloat16 l0 = __float2bfloat16(v.x - __bfloat162float(h0));
    __hip_bfloat16 l1 = __float2bfloat16(v.y - __bfloat162float(h1));
    __hip_bfloat16 l2 = __float2bfloat16(v.z - __bfloat162float(h2));
    __hip_bfloat16 l3 = __float2bfloat16(v.w - __bfloat162float(h3));
    union { __hip_bfloat16 h[4]; short4 s; } uh, ul;
    uh.h[0] = h0; uh.h[1] = h1; uh.h[2] = h2; uh.h[3] = h3;
    ul.h[0] = l0; ul.h[1] = l1; ul.h[2] = l2; ul.h[3] = l3;
    ((short4*)hi)[i4] = uh.s;
    ((short4*)lo)[i4] = ul.s;
}

// ============ W [K][N] fp32 -> WT hi/lo [Npad][K] bf16 (zero-padded) ========
__global__ __launch_bounds__(256) void transpose_split_kernel(
    const float* __restrict__ in,
    __hip_bfloat16* __restrict__ outH, __hip_bfloat16* __restrict__ outL,
    int K, int N)
{
    __shared__ float tile[32][33];
    const int k0 = blockIdx.y * 32, n0 = blockIdx.x * 32;
    const int t = threadIdx.x;
    const int lr = t >> 5, lc = t & 31;
    #pragma unroll
    for (int p = 0; p < 4; p++) {
        const int r = p * 8 + lr;
        const int n = n0 + lc;
        tile[r][lc] = (n < N) ? in[(size_t)(k0 + r) * N + n] : 0.f;
    }
    __syncthreads();
    #pragma unroll
    for (int p = 0; p < 4; p++) {
        const int r = p * 8 + lr;
        const float v = tile[lc][r];
        const __hip_bfloat16 h = __float2bfloat16(v);
        const __hip_bfloat16 l = __float2bfloat16(v - __bfloat162float(h));
        outH[(size_t)(n0 + r) * K + k0 + lc] = h;
        outL[(size_t)(n0 + r) * K + k0 + lc] = l;
    }
}

// ===================== bf16x3 split-MFMA GEMM body (r0-exact loop) ==========
// C = act(A @ BT^T + bias [+ rank2]); A = Ahi+Alo [M][512], BT = Bhi+Blo
// [Npad][512]. 128x128 tile, 4 waves 2x2, 16x16x32 MFMA, 3 MFMA per frag,
// single-buffered row-major LDS (32KB), 2 barriers per K-step.
// NEW vs r0: bijective m-chunked XCD swizzle (gridDim.y % 8 == 0):
//   xcd = L&7 owns m-blocks [xcd*(gy/8), ...), n fastest within.
// SPLIT:  C written as bf16 hi/lo pair (N=512).
// !SPLIT: C written fp32 to Cf (ldc), bounds-checked against N.
template<bool GELU, bool RANK2, bool SPLIT, bool BOUNDS>
__device__ __forceinline__ void gemm3k_body(
    const __hip_bfloat16* __restrict__ Ahi, const __hip_bfloat16* __restrict__ Alo,
    const __hip_bfloat16* __restrict__ Bhi, const __hip_bfloat16* __restrict__ Blo,
    const float* __restrict__ bias,
    float* __restrict__ Cf, int ldc,
    __hip_bfloat16* __restrict__ Chi, __hip_bfloat16* __restrict__ Clo,
    int N,
    const float* __restrict__ A2, const float* __restrict__ W2r)
{
    __shared__ __align__(16) __hip_bfloat16 AsH[128][32];
    __shared__ __align__(16) __hip_bfloat16 AsL[128][32];
    __shared__ __align__(16) __hip_bfloat16 BsH[128][32];
    __shared__ __align__(16) __hip_bfloat16 BsL[128][32];
    const int t = threadIdx.x;
    const int wave = t >> 6, lane = t & 63;
    const int wave_m = wave >> 1, wave_n = wave & 1;
    const int fr = lane & 15, quad = lane >> 4;
    // m-chunked XCD swizzle (bijective: gridDim.y % 8 == 0)
    const int gx = gridDim.x;
    const int L = blockIdx.y * gx + blockIdx.x;
    const int xcd = L & 7, rem = L >> 3;
    const int mchunk = gridDim.y >> 3;
    const int m0 = (xcd * mchunk + rem / gx) * 128;
    const int n0 = (rem % gx) * 128;
    const int srow = lane >> 2;
    const int skc  = (lane & 3) * 8;

    f32x4 acc[4][4] = {};

    for (int k0 = 0; k0 < 512; k0 += 32) {
        #pragma unroll
        for (int s = 0; s < 2; s++) {
            const int seg = wave * 2 + s;
            const int row = seg * 16 + srow;
            const size_t ao = (size_t)(m0 + row) * 512 + k0 + skc;
            const size_t bo = (size_t)(n0 + row) * 512 + k0 + skc;
            async_copy16(Ahi + ao, &AsH[seg * 16][0]);
            async_copy16(Alo + ao, &AsL[seg * 16][0]);
            async_copy16(Bhi + bo, &BsH[seg * 16][0]);
            async_copy16(Blo + bo, &BsL[seg * 16][0]);
        }
        __syncthreads();
        bf16x8 ah[4], al[4], bh[4], bl[4];
        #pragma unroll
        for (int i = 0; i < 4; i++) {
            ah[i] = *(const bf16x8*)&AsH[wave_m * 64 + i * 16 + fr][quad * 8];
            al[i] = *(const bf16x8*)&AsL[wave_m * 64 + i * 16 + fr][quad * 8];
        }
        #pragma unroll
        for (int j = 0; j < 4; j++) {
            bh[j] = *(const bf16x8*)&BsH[wave_n * 64 + j * 16 + fr][quad * 8];
            bl[j] = *(const bf16x8*)&BsL[wave_n * 64 + j * 16 + fr][quad * 8];
        }
        #pragma unroll
        for (int i = 0; i < 4; i++)
            #pragma unroll
            for (int j = 0; j < 4; j++)
                acc[i][j] = __builtin_amdgcn_mfma_f32_16x16x32_bf16(
                    ah[i], bh[j], acc[i][j], 0, 0, 0);
        #pragma unroll
        for (int i = 0; i < 4; i++)
            #pragma unroll
            for (int j = 0; j < 4; j++)
                acc[i][j] = __builtin_amdgcn_mfma_f32_16x16x32_bf16(
                    ah[i], bl[j], acc[i][j], 0, 0, 0);
        #pragma unroll
        for (int i = 0; i < 4; i++)
            #pragma unroll
            for (int j = 0; j < 4; j++)
                acc[i][j] = __builtin_amdgcn_mfma_f32_16x16x32_bf16(
                    al[i], bh[j], acc[i][j], 0, 0, 0);
        __syncthreads();
    }

    // epilogue: row = m0 + wave_m*64 + i*16 + quad*4 + r,
    //           col = n0 + wave_n*64 + j*16 + fr
    #pragma unroll
    for (int i = 0; i < 4; i++) {
        const int gmb = m0 + wave_m * 64 + i * 16 + quad * 4;
        #pragma unroll
        for (int j = 0; j < 4; j++) {
            const int gn = n0 + wave_n * 64 + j * 16 + fr;
            const bool nok = !BOUNDS || (gn < N);
            const float bv = nok ? bias[gn] : 0.f;
            float w2a = 0.f, w2b = 0.f;
            if (RANK2) { w2a = W2r[gn]; w2b = W2r[512 + gn]; }
            #pragma unroll
            for (int r = 0; r < 4; r++) {
                const int gm = gmb + r;
                float v = acc[i][j][r] + bv;
                if (RANK2)
                    v += A2[(size_t)gm * 2] * w2a + A2[(size_t)gm * 2 + 1] * w2b;
                if (GELU) v = gelu_exact(v);
                if (SPLIT) {
                    const __hip_bfloat16 h = __float2bfloat16(v);
                    const __hip_bfloat16 l =
                        __float2bfloat16(v - __bfloat162float(h));
                    Chi[(size_t)gm * 512 + gn] = h;
                    Clo[(size_t)gm * 512 + gn] = l;
                } else if (nok) {
                    Cf[(size_t)gm * ldc + gn] = v;
                }
            }
        }
    }
}

// -------- named wrappers (distinct Kernel_Name for rocprof attribution) -----
__global__ __launch_bounds__(256) void gemm_h1(
    const __hip_bfloat16* __restrict__ Ahi, const __hip_bfloat16* __restrict__ Alo,
    const __hip_bfloat16* __restrict__ Bhi, const __hip_bfloat16* __restrict__ Blo,
    const float* __restrict__ bias,
    __hip_bfloat16* __restrict__ Chi, __hip_bfloat16* __restrict__ Clo)
{
    gemm3k_body<true, false, true, false>(
        Ahi, Alo, Bhi, Blo, bias, nullptr, 0, Chi, Clo, 512, nullptr, nullptr);
}

__global__ __launch_bounds__(256) void gemm_df(
    const __hip_bfloat16* __restrict__ Ahi, const __hip_bfloat16* __restrict__ Alo,
    const __hip_bfloat16* __restrict__ Bhi, const __hip_bfloat16* __restrict__ Blo,
    const float* __restrict__ bias,
    __hip_bfloat16* __restrict__ Chi, __hip_bfloat16* __restrict__ Clo)
{
    gemm3k_body<true, false, true, false>(
        Ahi, Alo, Bhi, Blo, bias, nullptr, 0, Chi, Clo, 512, nullptr, nullptr);
}

__global__ __launch_bounds__(256) void gemm_h3(
    const __hip_bfloat16* __restrict__ Ahi, const __hip_bfloat16* __restrict__ Alo,
    const __hip_bfloat16* __restrict__ Bhi, const __hip_bfloat16* __restrict__ Blo,
    const float* __restrict__ bias,
    __hip_bfloat16* __restrict__ Chi, __hip_bfloat16* __restrict__ Clo,
    const float* __restrict__ A2, const float* __restrict__ W2r)
{
    gemm3k_body<true, true, true, false>(
        Ahi, Alo, Bhi, Blo, bias, nullptr, 0, Chi, Clo, 512, A2, W2r);
}

__global__ __launch_bounds__(256) void gemm_ef(
    const __hip_bfloat16* __restrict__ Ahi, const __hip_bfloat16* __restrict__ Alo,
    const __hip_bfloat16* __restrict__ Bhi, const __hip_bfloat16* __restrict__ Blo,
    const float* __restrict__ bias,
    float* __restrict__ Cf)
{
    gemm3k_body<false, false, false, true>(
        Ahi, Alo, Bhi, Blo, bias, Cf, 1027, nullptr, nullptr, 1027,
        nullptr, nullptr);
}

// ===================== small pre-selection kernels (r0-exact) ===============
// coords = df@Wc + bc : one wave per row, df from hi/lo pair
__global__ __launch_bounds__(256) void coords_kernel(
    const __hip_bfloat16* __restrict__ DFh, const __hip_bfloat16* __restrict__ DFl,
    const float* __restrict__ Wc,
    const float* __restrict__ bc, float* __restrict__ CRD)
{
    const int gid  = blockIdx.x * 256 + threadIdx.x;
    const int row  = gid >> 6;
    const int lane = gid & 63;
    const __hip_bfloat16* dh = DFh + (size_t)row * 512;
    const __hip_bfloat16* dl = DFl + (size_t)row * 512;
    float s0 = 0.f, s1 = 0.f;
    for (int k = lane; k < 512; k += 64) {
        const float v = __bfloat162float(dh[k]) + __bfloat162float(dl[k]);
        const float2 wc = ((const float2*)Wc)[k];
        s0 += v * wc.x;
        s1 += v * wc.y;
    }
    #pragma unroll
    for (int off = 32; off; off >>= 1) {
        s0 += __shfl_down(s0, off);
        s1 += __shfl_down(s1, off);
    }
    if (lane == 0) {
        CRD[(size_t)row * 2 + 0] = s0 + bc[0];
        CRD[(size_t)row * 2 + 1] = s1 + bc[1];
    }
}

__global__ __launch_bounds__(256) void importance_kernel(
    const float* __restrict__ EF, float* __restrict__ IMP)
{
    const int gid  = blockIdx.x * 256 + threadIdx.x;
    const int row  = gid >> 6;
    const int lane = gid & 63;
    const float* e = EF + (size_t)row * 1027;
    float ss = 0.f;
    for (int k = lane; k < 1027; k += 64) { const float v = e[k]; ss += v * v; }
    #pragma unroll
    for (int off = 32; off; off >>= 1) ss += __shfl_down(ss, off);
    if (lane == 0) IMP[row] = sqrtf(ss);
}

// ===================== selection ============================================
__global__ __launch_bounds__(1024) void topk_kernel(
    const float* __restrict__ IMP, int* __restrict__ IDX)
{
    __shared__ float v[4096];
    __shared__ int   ix[4096];
    const int b = blockIdx.x, t = threadIdx.x;
    for (int i = t; i < 4096; i += 1024) { v[i] = IMP[b * 4096 + i]; ix[i] = i; }
    __syncthreads();
    for (int k = 2; k <= 4096; k <<= 1) {
        for (int j = k >> 1; j > 0; j >>= 1) {
            for (int q = 0; q < 4; q++) {
                const int i = t + (q << 10);
                const int l = i ^ j;
                if (l > i) {
                    const float vi = v[i], vl = v[l];
                    const int   ii = ix[i], il = ix[l];
                    const bool after = (vi < vl) || (vi == vl && ii > il);
                    const bool dirAsc = ((i & k) == 0);
                    if (dirAsc ? after : !after) {
                        v[i] = vl; v[l] = vi; ix[i] = il; ix[l] = ii;
                    }
                }
            }
            __syncthreads();
        }
    }
    if (t < 512) IDX[b * 512 + t] = ix[t];
}

__global__ __launch_bounds__(256) void gather_kernel(
    const float* __restrict__ EF, const int* __restrict__ IDX,
    float* __restrict__ POS, __hip_bfloat16* __restrict__ ST)
{
    const int bn  = blockIdx.x;
    const int b   = bn >> 9;
    const int row = IDX[bn];
    const float* src = EF + ((size_t)(b * 4096) + row) * 1027;
    const int t = threadIdx.x;
    if (t < 2) POS[(size_t)bn * 2 + t] = src[t];
    __hip_bfloat16* dst = ST + (size_t)bn * 1024;
    for (int k = t; k < 1024; k += 256) dst[k] = __float2bfloat16(src[2 + k]);
}

// ===================== weight transpose + fp32->bf16 (post-sel) =============
__global__ __launch_bounds__(256) void transpose_cvt_kernel(
    const float* __restrict__ in, __hip_bfloat16* __restrict__ out,
    int K, int N)
{
    __shared__ float tile[32][33];
    const int k0 = blockIdx.y * 32, n0 = blockIdx.x * 32;
    const int t = threadIdx.x;
    const int lr = t >> 5, lc = t & 31;
    #pragma unroll
    for (int p = 0; p < 4; p++) {
        const int r = p * 8 + lr;
        tile[r][lc] = in[(size_t)(k0 + r) * N + n0 + lc];
    }
    __syncthreads();
    #pragma unroll
    for (int p = 0; p < 4; p++) {
        const int r = p * 8 + lr;
        out[(size_t)(n0 + r) * K + k0 + lc] = __float2bfloat16(tile[lc][r]);
    }
}

__global__ __launch_bounds__(256) void transpose_proj_kernel(
    const __hip_bfloat16* __restrict__ in, __hip_bfloat16* __restrict__ out)
{
    __shared__ __hip_bfloat16 tile[32][33];
    const int b = blockIdx.z;
    const int n0 = blockIdx.y * 32, d0 = blockIdx.x * 32;
    const int t = threadIdx.x;
    const int lr = t >> 5, lc = t & 31;
    #pragma unroll
    for (int p = 0; p < 4; p++) {
        const int r = p * 8 + lr;
        tile[r][lc] = in[((size_t)b * 512 + n0 + r) * 512 + d0 + lc];
    }
    __syncthreads();
    #pragma unroll
    for (int p = 0; p < 4; p++) {
        const int r = p * 8 + lr;
        out[((size_t)b * 512 + d0 + r) * 512 + n0 + lc] = tile[lc][r];
    }
}

// ===================== bf16 MFMA GEMM (post-selection, dbuf) ================
template<bool GELU>
__device__ __forceinline__ void gemm_post_body(
    const __hip_bfloat16* __restrict__ A,
    const __hip_bfloat16* __restrict__ BT,
    const float* __restrict__ bias,
    __hip_bfloat16* __restrict__ C,
    int N, int K)
{
    __shared__ __align__(16) __hip_bfloat16 As[2][128][32];
    __shared__ __align__(16) __hip_bfloat16 Bs[2][128][32];
    const int t = threadIdx.x;
    const int wave = t >> 6, lane = t & 63;
    const int wave_m = wave >> 1, wave_n = wave & 1;
    const int fr = lane & 15, quad = lane >> 4;
    const int gx = gridDim.x;
    const int nwg = gx * gridDim.y;
    int lid = blockIdx.y * gx + blockIdx.x;
    {
        const int chunk = nwg >> 3;
        lid = (lid & 7) * chunk + (lid >> 3);
    }
    const int m0 = (lid / gx) * 128;
    const int n0 = (lid % gx) * 128;
    const int srow = lane >> 2;
    const int skc  = (lane & 3) * 8;
    const int nsteps = K >> 5;

    f32x4 acc[4][4] = {};

    auto STAGE = [&](int buf, int step) {
        const int kk = step << 5;
        #pragma unroll
        for (int s = 0; s < 2; s++) {
            const int seg = wave * 2 + s;
            const int row = seg * 16 + srow;
            async_copy16(A  + (size_t)(m0 + row) * K + kk + skc,
                         &As[buf][seg * 16][0]);
            async_copy16(BT + (size_t)(n0 + row) * K + kk + skc,
                         &Bs[buf][seg * 16][0]);
        }
    };

    STAGE(0, 0);
    __syncthreads();
    int cur = 0;
    for (int step = 0; step < nsteps; ++step) {
        if (step + 1 < nsteps) STAGE(cur ^ 1, step + 1);
        bf16x8 af[4], bfv[4];
        #pragma unroll
        for (int i = 0; i < 4; i++)
            af[i] = *(const bf16x8*)&As[cur][wave_m * 64 + i * 16 + fr][quad * 8];
        #pragma unroll
        for (int j = 0; j < 4; j++)
            bfv[j] = *(const bf16x8*)&Bs[cur][wave_n * 64 + j * 16 + fr][quad * 8];
        #pragma unroll
        for (int i = 0; i < 4; i++)
            #pragma unroll
            for (int j = 0; j < 4; j++)
                acc[i][j] = __builtin_amdgcn_mfma_f32_16x16x32_bf16(
                    af[i], bfv[j], acc[i][j], 0, 0, 0);
        __syncthreads();
        cur ^= 1;
    }
    #pragma unroll
    for (int i = 0; i < 4; i++) {
        const int gm = m0 + wave_m * 64 + i * 16 + quad * 4;
        #pragma unroll
        for (int j = 0; j < 4; j++) {
            const int gn = n0 + wave_n * 64 + j * 16 + fr;
            const float bv = bias[gn];
            #pragma unroll
            for (int r = 0; r < 4; r++) {
                float v = acc[i][j][r] + bv;
                if (GELU) v = gelu_exact(v);
                C[(size_t)(gm + r) * N + gn] = __float2bfloat16(v);
            }
        }
    }
}

__global__ __launch_bounds__(256, 4) void gemm_o1(
    const __hip_bfloat16* __restrict__ A, const __hip_bfloat16* __restrict__ BT,
    const float* __restrict__ bias, __hip_bfloat16* __restrict__ C,
    int N, int K)
{
    gemm_post_body<true>(A, BT, bias, C, N, K);
}

__global__ __launch_bounds__(256, 4) void gemm_o2(
    const __hip_bfloat16* __restrict__ A, const __hip_bfloat16* __restrict__ BT,
    const float* __restrict__ bias, __hip_bfloat16* __restrict__ C,
    int N, int K)
{
    gemm_post_body<false>(A, BT, bias, C, N, K);
}

// ===================== fused attention output (bf16 MFMA) ===================
__global__ __launch_bounds__(256) void attn_mfma_kernel(
    const float* __restrict__ POS,
    const __hip_bfloat16* __restrict__ PROJT,
    float* __restrict__ OUT)
{
    __shared__ __align__(16) __hip_bfloat16 Bs[256][32];
    __shared__ float2 pos_s[512];
    __shared__ float srow_s[4][16];
    const int t = threadIdx.x;
    const int wave = t >> 6, lane = t & 63;
    const int fr = lane & 15, quad = lane >> 4;
    const int b  = blockIdx.z;
    const int g0 = blockIdx.x * 64;
    const int d0 = blockIdx.y * 256;

    {
        const float2* p = (const float2*)(POS + (size_t)b * 512 * 2);
        pos_s[t]       = p[t];
        pos_s[256 + t] = p[256 + t];
    }
    const int g = g0 + wave * 16 + fr;
    const bool gv = g < 10000;
    const float step = 2.0f / 99.0f;
    const int gi = gv ? (g / 100) : 0;
    const int gj = gv ? (g - gi * 100) : 0;
    const float gx = -1.f + step * (float)gi;
    const float gy = -1.f + step * (float)gj;

    f32x4 acc[16] = {};
    float wsum = 0.f;
    __syncthreads();

    for (int n0 = 0; n0 < 512; n0 += 32) {
        #pragma unroll
        for (int s = 0; s < 4; s++) {
            const int seg = wave * 4 + s;
            const __hip_bfloat16* gB = PROJT
                + ((size_t)b * 512 + d0 + seg * 16 + (lane >> 2)) * 512
                + n0 + (lane & 3) * 8;
            async_copy16(gB, &Bs[seg * 16][0]);
        }
        bf16x8 wf;
        float wl = 0.f;
        #pragma unroll
        for (int j = 0; j < 8; j++) {
            const int n = n0 + quad * 8 + j;
            const float2 pn = pos_s[n];
            const float dx = gx - pn.x, dy = gy - pn.y;
            const float w = gv ? __expf(-10.0f * (dx * dx + dy * dy)) : 0.f;
            const __hip_bfloat16 wb = __float2bfloat16(w);
            union { __hip_bfloat16 h; short s; } u; u.h = wb;
            wf[j] = u.s;
            wl += __bfloat162float(wb);
        }
        wsum += wl;
        __syncthreads();
        #pragma unroll
        for (int j = 0; j < 16; j++) {
            const bf16x8 bv = *(const bf16x8*)&Bs[j * 16 + fr][quad * 8];
            acc[j] = __builtin_amdgcn_mfma_f32_16x16x32_bf16(wf, bv, acc[j], 0, 0, 0);
        }
        __syncthreads();
    }
    wsum += __shfl_xor(wsum, 16);
    wsum += __shfl_xor(wsum, 32);
    if (lane < 16) srow_s[wave][lane] = wsum;
    __syncthreads();
    const int rbase = quad * 4;
    float inv[4];
    #pragma unroll
    for (int r = 0; r < 4; r++)
        inv[r] = 1.0f / (srow_s[wave][rbase + r] + 1e-8f);
    #pragma unroll
    for (int j = 0; j < 16; j++) {
        const int col = d0 + j * 16 + fr;
        #pragma unroll
        for (int r = 0; r < 4; r++) {
            const int gr = g0 + wave * 16 + rbase + r;
            if (gr < 10000)
                OUT[((size_t)b * 10000 + gr) * 512 + col] = acc[j][r] * inv[r];
        }
    }
}

// ===========================================================================
extern "C" void kernel_launch(void* const* d_in, const int* in_sizes, int n_in,
                              void* d_out, int out_size, void* d_ws, size_t ws_size,
                              hipStream_t stream)
{
    const float* x   = (const float*)d_in[0];
    const float* W1  = (const float*)d_in[1];
    const float* b1  = (const float*)d_in[2];
    const float* W2  = (const float*)d_in[3];
    const float* b2  = (const float*)d_in[4];
    const float* Wc  = (const float*)d_in[5];
    const float* bc  = (const float*)d_in[6];
    const float* We1 = (const float*)d_in[7];
    const float* be1 = (const float*)d_in[8];
    const float* We2 = (const float*)d_in[9];
    const float* be2 = (const float*)d_in[10];
    const float* Wo1 = (const float*)d_in[11];
    const float* bo1 = (const float*)d_in[12];
    const float* Wo2 = (const float*)d_in[13];
    const float* bo2 = (const float*)d_in[14];
    float* out = (float*)d_out;

    const size_t BS = 32768;
    const size_t ACT = BS * 512;             // elements per activation matrix
    // ---- workspace layout ----
    __hip_bfloat16* P0h = (__hip_bfloat16*)d_ws;        // 32 MB
    __hip_bfloat16* P0l = P0h + ACT;                    // 32 MB
    __hip_bfloat16* P1h = P0l + ACT;                    // 32 MB
    __hip_bfloat16* P1l = P1h + ACT;                    // 32 MB
    float* EF  = (float*)(P1l + ACT);                   // 32768x1027 fp32
    float* CRD = EF + BS * 1027;                        // 32768x2
    float* IMP = CRD + BS * 2;                          // 32768
    int*   IDX = (int*)(IMP + BS);                      // 4096
    float* POS = (float*)(IDX + 4096);                  // 4096x2
    __hip_bfloat16* W1Th = (__hip_bfloat16*)(POS + 4096 * 2);   // 512x512
    __hip_bfloat16* W1Tl = W1Th + 512 * 512;
    __hip_bfloat16* W2Th = W1Tl + 512 * 512;
    __hip_bfloat16* W2Tl = W2Th + 512 * 512;
    __hip_bfloat16* We1Th = W2Tl + 512 * 512;
    __hip_bfloat16* We1Tl = We1Th + 512 * 512;
    __hip_bfloat16* We2Th = We1Tl + 512 * 512;          // 1152x512
    __hip_bfloat16* We2Tl = We2Th + (size_t)1152 * 512;
    // post-selection pool aliases P0 (dead after h3 GEMM)
    __hip_bfloat16* ST    = P0h;                           // 4096x1024
    __hip_bfloat16* H4    = ST + (size_t)4096 * 1024;      // 4096x2048
    __hip_bfloat16* PROJ  = H4 + (size_t)4096 * 2048;      // 4096x512
    __hip_bfloat16* PROJT = PROJ + (size_t)4096 * 512;     // 8x512x512
    __hip_bfloat16* Wo1T  = PROJT + (size_t)4096 * 512;    // 2048x1024
    __hip_bfloat16* Wo2T  = Wo1T + (size_t)2048 * 1024;    // 512x2048

    dim3 blk(256);
    // ---- prep: split x, split+transpose pre-selection weights ----
    split_kernel<<<dim3(16384), blk, 0, stream>>>(x, P0h, P0l);
    transpose_split_kernel<<<dim3(16, 16), blk, 0, stream>>>(W1, W1Th, W1Tl, 512, 512);
    transpose_split_kernel<<<dim3(16, 16), blk, 0, stream>>>(W2, W2Th, W2Tl, 512, 512);
    transpose_split_kernel<<<dim3(16, 16), blk, 0, stream>>>(We1 + 2 * 512, We1Th, We1Tl, 512, 512);
    transpose_split_kernel<<<dim3(36, 16), blk, 0, stream>>>(We2, We2Th, We2Tl, 512, 1027);
    // ---- pre-selection (bf16x3 MFMA, r0-exact loop + XCD swizzle) ----
    // h1 = gelu(x@W1+b1) -> P1 pair
    gemm_h1<<<dim3(4, 256), blk, 0, stream>>>(
        P0h, P0l, W1Th, W1Tl, b1, P1h, P1l);
    // df = gelu(h1@W2+b2) -> P0 pair
    gemm_df<<<dim3(4, 256), blk, 0, stream>>>(
        P1h, P1l, W2Th, W2Tl, b2, P0h, P0l);
    // coords = df@Wc + bc
    coords_kernel<<<dim3(8192), blk, 0, stream>>>(P0h, P0l, Wc, bc, CRD);
    // h3 = gelu(df@We1[2:] + coords@We1[:2] + be1) -> P1 pair
    gemm_h3<<<dim3(4, 256), blk, 0, stream>>>(
        P0h, P0l, We1Th, We1Tl, be1, P1h, P1l, CRD, We1);
    // ef = h3@We2+be2 -> EF fp32 (N=1027)
    gemm_ef<<<dim3(9, 256), blk, 0, stream>>>(
        P1h, P1l, We2Th, We2Tl, be2, EF);
    // ---- selection ----
    importance_kernel<<<dim3(8192), blk, 0, stream>>>(EF, IMP);
    topk_kernel<<<dim3(8), dim3(1024), 0, stream>>>(IMP, IDX);
    // ---- post-selection weight prep ----
    transpose_cvt_kernel<<<dim3(64, 32), blk, 0, stream>>>(Wo1, Wo1T, 1024, 2048);
    transpose_cvt_kernel<<<dim3(16, 64), blk, 0, stream>>>(Wo2, Wo2T, 2048, 512);
    gather_kernel<<<dim3(4096), blk, 0, stream>>>(EF, IDX, POS, ST);
    // ---- post-selection (bf16 MFMA, dbuf) ----
    gemm_o1<<<dim3(16, 32), blk, 0, stream>>>(ST, Wo1T, bo1, H4, 2048, 1024);
    gemm_o2<<<dim3(4, 32), blk, 0, stream>>>(H4, Wo2T, bo2, PROJ, 512, 2048);
    transpose_proj_kernel<<<dim3(16, 16, 8), blk, 0, stream>>>(PROJ, PROJT);
    attn_mfma_kernel<<<dim3(157, 2, 8), blk, 0, stream>>>(POS, PROJT, out);
}